// Round 2
// baseline (3404.465 us; speedup 1.0000x reference)
//
#include <hip/hip_runtime.h>

#define B_   64
#define T_   256
#define E_   1024
#define H_   16
#define HD_  64
#define NTOK (B_*T_)          // 16384
#define LNEPS 1e-5f

#define BK   32
#define LDSS 68               // LDS row stride (floats): 16B-aligned float4 rows, breaks pow2 conflicts

// ---------- per-token LayerNorm stats (mu, rstd): one wave per token ----------
__global__ __launch_bounds__(256) void stats_kernel(
    const float* __restrict__ x, float2* __restrict__ st)
{
  int lane  = threadIdx.x & 63;
  int token = (blockIdx.x << 2) + (threadIdx.x >> 6);
  const float4* xr = (const float4*)(x + (size_t)token * E_);
  float s = 0.f, ss = 0.f;
  #pragma unroll
  for (int i = 0; i < 4; ++i) {
    float4 v = xr[lane + 64 * i];
    s += v.x + v.y + v.z + v.w;
    ss = fmaf(v.x, v.x, fmaf(v.y, v.y, fmaf(v.z, v.z, fmaf(v.w, v.w, ss))));
  }
  #pragma unroll
  for (int off = 32; off > 0; off >>= 1) {
    s  += __shfl_down(s,  off);
    ss += __shfl_down(ss, off);
  }
  if (lane == 0) {
    float mu  = s * (1.f / E_);
    float var = ss * (1.f / E_) - mu * mu;
    st[token] = make_float2(mu, rsqrtf(var + LNEPS));
  }
}

// ---------- generic 64x64-tile fp32 GEMM over M=16384, N=1024, K=1024 ----------
// MODE 0: A row-major plain. MODE 1: A row-major with LN fused (stats,g,b).
// MODE 2: A is attention output in (b,h,t,d) layout (strides 262144,16384,64,1).
template <int MODE>
__global__ __launch_bounds__(256) void gemm_k(
    const float* __restrict__ A, const float* __restrict__ W,
    const float* __restrict__ bias, const float* __restrict__ resid,
    const float2* __restrict__ stats,
    const float* __restrict__ lng, const float* __restrict__ lnb,
    float* __restrict__ C, int relu)
{
  __shared__ __align__(16) float Ast[BK * LDSS];   // Ast[k][m]
  __shared__ __align__(16) float Ws [BK * LDSS];   // Ws[k][n]
  const int row0 = blockIdx.x * 64, col0 = blockIdx.y * 64;
  const int tid = threadIdx.x;
  const int ar = tid >> 2, ac = (tid & 3) << 3;    // A stage: row ar, 8 k at ac
  const int wr = tid >> 3, wc = (tid & 7) << 3;    // W stage: k-row wr, 8 n at wc
  const int tx = tid & 15, ty = tid >> 4;          // compute: 4x4 at (ty*4, tx*4)

  float mu = 0.f, rstd = 0.f;
  if (MODE == 1) { float2 s2 = stats[row0 + ar]; mu = s2.x; rstd = s2.y; }

  const float* Abase;
  if (MODE == 2) {
    int b = row0 >> 8, t = (row0 & 255) + ar;      // 64-row tiles never cross a batch
    Abase = A + (size_t)b * (H_ * T_ * HD_) + (size_t)t * HD_;
  } else {
    Abase = A + (size_t)(row0 + ar) * E_;
  }

  float acc[4][4];
  #pragma unroll
  for (int i = 0; i < 4; ++i)
    #pragma unroll
    for (int j = 0; j < 4; ++j) acc[i][j] = 0.f;

  for (int k0 = 0; k0 < E_; k0 += BK) {
    float4 a0, a1;
    if (MODE == 2) {
      int e = k0 + ac;
      const float* ap = Abase + (size_t)(e >> 6) * (T_ * HD_) + (e & 63);
      a0 = *(const float4*)ap; a1 = *(const float4*)(ap + 4);
    } else {
      const float* ap = Abase + k0 + ac;
      a0 = *(const float4*)ap; a1 = *(const float4*)(ap + 4);
    }
    const float* wp = W + (size_t)(k0 + wr) * E_ + col0 + wc;
    float4 w0 = *(const float4*)wp, w1 = *(const float4*)(wp + 4);

    float av[8] = {a0.x, a0.y, a0.z, a0.w, a1.x, a1.y, a1.z, a1.w};
    if (MODE == 1) {
      float4 g0 = *(const float4*)(lng + k0 + ac);
      float4 g1 = *(const float4*)(lng + k0 + ac + 4);
      float4 b0 = *(const float4*)(lnb + k0 + ac);
      float4 b1 = *(const float4*)(lnb + k0 + ac + 4);
      float gv[8] = {g0.x, g0.y, g0.z, g0.w, g1.x, g1.y, g1.z, g1.w};
      float bv[8] = {b0.x, b0.y, b0.z, b0.w, b1.x, b1.y, b1.z, b1.w};
      #pragma unroll
      for (int j = 0; j < 8; ++j) av[j] = (av[j] - mu) * rstd * gv[j] + bv[j];
    }

    __syncthreads();                               // prev tile fully consumed
    #pragma unroll
    for (int j = 0; j < 8; ++j) Ast[(ac + j) * LDSS + ar] = av[j];
    *(float4*)(Ws + wr * LDSS + wc    ) = w0;
    *(float4*)(Ws + wr * LDSS + wc + 4) = w1;
    __syncthreads();

    #pragma unroll
    for (int kk = 0; kk < BK; ++kk) {
      float4 a4 = *(const float4*)(Ast + kk * LDSS + (ty << 2));
      float4 b4 = *(const float4*)(Ws  + kk * LDSS + (tx << 2));
      float av2[4] = {a4.x, a4.y, a4.z, a4.w};
      float bv2[4] = {b4.x, b4.y, b4.z, b4.w};
      #pragma unroll
      for (int i = 0; i < 4; ++i)
        #pragma unroll
        for (int j = 0; j < 4; ++j)
          acc[i][j] = fmaf(av2[i], bv2[j], acc[i][j]);
    }
  }

  float4 bc = make_float4(0.f, 0.f, 0.f, 0.f);
  if (bias) bc = *(const float4*)(bias + col0 + (tx << 2));
  #pragma unroll
  for (int i = 0; i < 4; ++i) {
    int r = row0 + (ty << 2) + i;
    float o0 = acc[i][0] + bc.x, o1 = acc[i][1] + bc.y;
    float o2 = acc[i][2] + bc.z, o3 = acc[i][3] + bc.w;
    if (relu) { o0 = fmaxf(o0, 0.f); o1 = fmaxf(o1, 0.f); o2 = fmaxf(o2, 0.f); o3 = fmaxf(o3, 0.f); }
    if (resid) {
      float4 rv = *(const float4*)(resid + (size_t)r * E_ + col0 + (tx << 2));
      o0 += rv.x; o1 += rv.y; o2 += rv.z; o3 += rv.w;
    }
    *(float4*)(C + (size_t)r * E_ + col0 + (tx << 2)) = make_float4(o0, o1, o2, o3);
  }
}

// ---------- QKV: LN1-fused per-head GEMM x(16384x1024) @ w[h](1024x64) -> (b,h,t,d) ----------
__global__ __launch_bounds__(256) void qkv_kernel(
    const float* __restrict__ x, const float2* __restrict__ stats,
    const float* __restrict__ lng, const float* __restrict__ lnb,
    const float* __restrict__ wk, const float* __restrict__ wq, const float* __restrict__ wv,
    float* __restrict__ ok, float* __restrict__ oq, float* __restrict__ ov)
{
  __shared__ __align__(16) float Ast[BK * LDSS];
  __shared__ __align__(16) float Ws [BK * LDSS];
  const int row0 = blockIdx.x * 64;
  const int head = blockIdx.y, z = blockIdx.z;
  const float* W = (z == 0 ? wk : z == 1 ? wq : wv) + (size_t)head * (E_ * HD_);
  float* O       = (z == 0 ? ok : z == 1 ? oq : ov);
  const int tid = threadIdx.x;
  const int ar = tid >> 2, ac = (tid & 3) << 3;
  const int wr = tid >> 3, wc = (tid & 7) << 3;
  const int tx = tid & 15, ty = tid >> 4;

  float2 s2 = stats[row0 + ar];
  const float mu = s2.x, rstd = s2.y;
  const float* Ap = x + (size_t)(row0 + ar) * E_;

  float acc[4][4];
  #pragma unroll
  for (int i = 0; i < 4; ++i)
    #pragma unroll
    for (int j = 0; j < 4; ++j) acc[i][j] = 0.f;

  for (int k0 = 0; k0 < E_; k0 += BK) {
    float4 a0 = *(const float4*)(Ap + k0 + ac);
    float4 a1 = *(const float4*)(Ap + k0 + ac + 4);
    const float* wp = W + (size_t)(k0 + wr) * HD_ + wc;
    float4 w0 = *(const float4*)wp, w1 = *(const float4*)(wp + 4);
    float4 g0 = *(const float4*)(lng + k0 + ac);
    float4 g1 = *(const float4*)(lng + k0 + ac + 4);
    float4 b0 = *(const float4*)(lnb + k0 + ac);
    float4 b1 = *(const float4*)(lnb + k0 + ac + 4);
    float av[8] = {a0.x, a0.y, a0.z, a0.w, a1.x, a1.y, a1.z, a1.w};
    float gv[8] = {g0.x, g0.y, g0.z, g0.w, g1.x, g1.y, g1.z, g1.w};
    float bv[8] = {b0.x, b0.y, b0.z, b0.w, b1.x, b1.y, b1.z, b1.w};
    #pragma unroll
    for (int j = 0; j < 8; ++j) av[j] = (av[j] - mu) * rstd * gv[j] + bv[j];

    __syncthreads();
    #pragma unroll
    for (int j = 0; j < 8; ++j) Ast[(ac + j) * LDSS + ar] = av[j];
    *(float4*)(Ws + wr * LDSS + wc    ) = w0;
    *(float4*)(Ws + wr * LDSS + wc + 4) = w1;
    __syncthreads();

    #pragma unroll
    for (int kk = 0; kk < BK; ++kk) {
      float4 a4 = *(const float4*)(Ast + kk * LDSS + (ty << 2));
      float4 b4 = *(const float4*)(Ws  + kk * LDSS + (tx << 2));
      float av2[4] = {a4.x, a4.y, a4.z, a4.w};
      float bv2[4] = {b4.x, b4.y, b4.z, b4.w};
      #pragma unroll
      for (int i = 0; i < 4; ++i)
        #pragma unroll
        for (int j = 0; j < 4; ++j)
          acc[i][j] = fmaf(av2[i], bv2[j], acc[i][j]);
    }
  }

  int b = row0 >> 8, t0 = row0 & 255;
  float* Cp = O + ((size_t)(b * H_ + head) * T_ + t0) * HD_;
  #pragma unroll
  for (int i = 0; i < 4; ++i)
    *(float4*)(Cp + (size_t)((ty << 2) + i) * HD_ + (tx << 2)) =
        make_float4(acc[i][0], acc[i][1], acc[i][2], acc[i][3]);
}

// ---------- fused causal attention, one block per (b,h); writes IN-PLACE over v ----------
// scores[t][s] = k_t . q_s / 8 (K.Q^T per reference), s <= t; out = softmax(scores) @ v.
// Output stays in (b,h,t,d) layout over d_out; proj GEMM (MODE 2) reads it head-decomposed.
__global__ __launch_bounds__(256) void attn_kernel(
    const float* __restrict__ kk_, const float* __restrict__ qq_,
    float* __restrict__ vio)
{
  __shared__ __align__(16) float Vb[T_ * HD_];   // 64 KB: whole V(b,h)
  __shared__ __align__(16) float Qb[64 * HD_];   // 16 KB: streamed Q tile
  const int bh  = blockIdx.x;
  const int tid = threadIdx.x, t = tid;
  const float* kb = kk_ + (size_t)bh * (T_ * HD_);
  const float* qb = qq_ + (size_t)bh * (T_ * HD_);
  float*       vb = vio + (size_t)bh * (T_ * HD_);

  // stage entire V into LDS (sole reader of this global region is this block)
  { const float4* s = (const float4*)vb; float4* d = (float4*)Vb;
    #pragma unroll
    for (int i = 0; i < 16; ++i) d[tid + 256 * i] = s[tid + 256 * i]; }

  // this thread's k row in registers
  float kreg[64];
  { const float4* s = (const float4*)(kb + (size_t)t * HD_);
    #pragma unroll
    for (int i = 0; i < 16; ++i) {
      float4 u = s[i];
      kreg[4*i] = u.x; kreg[4*i+1] = u.y; kreg[4*i+2] = u.z; kreg[4*i+3] = u.w;
    } }

  // pass A: running max + sumexp over s <= t
  float m = -1e30f, l = 0.f;
  for (int st = 0; st < 4; ++st) {
    __syncthreads();
    { const float4* s = (const float4*)(qb + (size_t)st * 64 * HD_); float4* d = (float4*)Qb;
      #pragma unroll
      for (int i = 0; i < 4; ++i) d[tid + 256 * i] = s[tid + 256 * i]; }
    __syncthreads();
    int sEnd = min(63, t - st * 64);
    for (int sl = 0; sl <= sEnd; ++sl) {
      const float* qr = Qb + sl * HD_;
      float dot = 0.f;
      #pragma unroll
      for (int j = 0; j < 64; ++j) dot = fmaf(kreg[j], qr[j], dot);
      float sc = dot * 0.125f;
      float mn = fmaxf(m, sc);
      l = l * __expf(m - mn) + __expf(sc - mn);
      m = mn;
    }
  }

  // pass B: recompute scores, accumulate P @ V (V from LDS)
  float acc[64];
  #pragma unroll
  for (int j = 0; j < 64; ++j) acc[j] = 0.f;
  for (int st = 0; st < 4; ++st) {
    __syncthreads();
    { const float4* s = (const float4*)(qb + (size_t)st * 64 * HD_); float4* d = (float4*)Qb;
      #pragma unroll
      for (int i = 0; i < 4; ++i) d[tid + 256 * i] = s[tid + 256 * i]; }
    __syncthreads();
    int sEnd = min(63, t - st * 64);
    for (int sl = 0; sl <= sEnd; ++sl) {
      const float* qr = Qb + sl * HD_;
      float dot = 0.f;
      #pragma unroll
      for (int j = 0; j < 64; ++j) dot = fmaf(kreg[j], qr[j], dot);
      float p = __expf(dot * 0.125f - m);
      const float* vr = Vb + (st * 64 + sl) * HD_;
      #pragma unroll
      for (int j = 0; j < 64; ++j) acc[j] = fmaf(p, vr[j], acc[j]);
    }
  }

  float inv = 1.0f / l;                 // s = t term always present -> l >= 1
  float4* op = (float4*)(vb + (size_t)t * HD_);
  #pragma unroll
  for (int i = 0; i < 16; ++i)
    op[i] = make_float4(acc[4*i] * inv, acc[4*i+1] * inv, acc[4*i+2] * inv, acc[4*i+3] * inv);
}

// ---------- launch ----------
extern "C" void kernel_launch(void* const* d_in, const int* in_sizes, int n_in,
                              void* d_out, int out_size, void* d_ws, size_t ws_size,
                              hipStream_t stream) {
  const float* x     = (const float*)d_in[0];
  const float* ln1g  = (const float*)d_in[1];
  const float* ln1b  = (const float*)d_in[2];
  const float* wk    = (const float*)d_in[3];
  const float* wq    = (const float*)d_in[4];
  const float* wv    = (const float*)d_in[5];
  const float* wproj = (const float*)d_in[6];
  const float* bproj = (const float*)d_in[7];
  const float* ln2g  = (const float*)d_in[8];
  const float* ln2b  = (const float*)d_in[9];
  const float* w1    = (const float*)d_in[10];
  const float* b1    = (const float*)d_in[11];
  const float* w2    = (const float*)d_in[12];
  const float* b2    = (const float*)d_in[13];
  float* outp = (float*)d_out;

  // ws: [k 64MB | q 64MB | stats 128KB]  (total 128.125 MB; round-1 proved >=128MB mapped)
  // liveness: k -> x1 (after attn); q -> ff1 (after proj); d_out: v -> attn -> out
  char* ws = (char*)d_ws;
  const size_t MATB = (size_t)NTOK * E_ * 4;     // 64 MiB per fp32 activation matrix
  float*  kbuf  = (float*)(ws);                  // k, then x1
  float*  qbuf  = (float*)(ws + MATB);           // q, then ff1
  float2* stats = (float2*)(ws + 2 * MATB);      // (mu, rstd) per token, reused LN1/LN2
  float*  vbuf  = outp;                          // v, then attn (bhtd), then final out

  // 1) LN1 stats
  stats_kernel<<<NTOK/4, 256, 0, stream>>>(x, stats);
  // 2) k,q,v = LN1(x) @ w{k,q,v}[head]  (LN fused into A-staging)
  qkv_kernel<<<dim3(NTOK/64, H_, 3), 256, 0, stream>>>(x, stats, ln1g, ln1b,
                                                       wk, wq, wv, kbuf, qbuf, vbuf);
  // 3) attn in-place over v (stays bhtd in d_out)
  attn_kernel<<<B_*H_, 256, 0, stream>>>(kbuf, qbuf, vbuf);
  // 4) x1 = x + attn @ w_proj + b_proj   (A in bhtd layout; x1 -> kbuf)
  gemm_k<2><<<dim3(NTOK/64, E_/64), 256, 0, stream>>>(vbuf, wproj, bproj, x,
                                                      nullptr, nullptr, nullptr, kbuf, 0);
  // 5) LN2 stats on x1
  stats_kernel<<<NTOK/4, 256, 0, stream>>>(kbuf, stats);
  // 6) ff1 = relu(LN2(x1) @ w1 + b1)   (LN fused; ff1 -> qbuf)
  gemm_k<1><<<dim3(NTOK/64, E_/64), 256, 0, stream>>>(kbuf, w1, b1, nullptr,
                                                      stats, ln2g, ln2b, qbuf, 1);
  // 7) out = x1 + ff1 @ w2 + b2
  gemm_k<0><<<dim3(NTOK/64, E_/64), 256, 0, stream>>>(qbuf, w2, b2, kbuf,
                                                      nullptr, nullptr, nullptr, outp, 0);
}

// Round 3
// 1468.997 us; speedup vs baseline: 2.3175x; 2.3175x over previous
//
#include <hip/hip_runtime.h>

typedef unsigned int u32;
typedef unsigned short u16;
typedef __attribute__((ext_vector_type(8))) short bf16x8;   // 8 bf16 in 4 VGPRs
typedef __attribute__((ext_vector_type(4))) float f32x4;

#define GLOBAL_AS __attribute__((address_space(1)))
#define LDS_AS    __attribute__((address_space(3)))

#define B_   64
#define T_   256
#define E_   1024
#define H_   16
#define HD_  64
#define NTOK (B_*T_)          // 16384
#define K_   1024
#define LNEPS 1e-5f

// ---------- bf16 helpers ----------
__device__ __forceinline__ float bflo(u32 u){ return __uint_as_float(u << 16); }
__device__ __forceinline__ float bfhi(u32 u){ return __uint_as_float(u & 0xffff0000u); }
__device__ __forceinline__ u16 f2bf(float f){            // round-to-nearest-even
  u32 x = __float_as_uint(f);
  u32 r = x + 0x7fffu + ((x >> 16) & 1u);
  return (u16)(r >> 16);
}
__device__ __forceinline__ u32 pack2(float a, float b){
  return (u32)f2bf(a) | ((u32)f2bf(b) << 16);
}

// async global->LDS, 16 B per lane (dest = wave-uniform base + lane*16)
__device__ __forceinline__ void gload16(const u16* g, u16* l){
  __builtin_amdgcn_global_load_lds((const GLOBAL_AS void*)g, (LDS_AS void*)l, 16, 0, 0);
}

// ---------- fused LayerNorm fp32 -> bf16, one wave per token ----------
__global__ __launch_bounds__(256) void ln_bf16_kernel(
    const float* __restrict__ x, const float* __restrict__ g,
    const float* __restrict__ b, u16* __restrict__ o)
{
  int lane  = threadIdx.x & 63;
  int token = (blockIdx.x << 2) + (threadIdx.x >> 6);
  const float4* xr = (const float4*)(x + (size_t)token * E_);
  float4 v[4];
  float s = 0.f, ss = 0.f;
  #pragma unroll
  for (int i = 0; i < 4; ++i){
    v[i] = xr[lane + 64 * i];
    s += v[i].x + v[i].y + v[i].z + v[i].w;
    ss = fmaf(v[i].x, v[i].x, fmaf(v[i].y, v[i].y,
         fmaf(v[i].z, v[i].z, fmaf(v[i].w, v[i].w, ss))));
  }
  #pragma unroll
  for (int off = 32; off > 0; off >>= 1){
    s  += __shfl_xor(s,  off);
    ss += __shfl_xor(ss, off);
  }
  float mu   = s * (1.f / E_);
  float var  = ss * (1.f / E_) - mu * mu;
  float rstd = rsqrtf(var + LNEPS);
  const float4* gr = (const float4*)g;
  const float4* br = (const float4*)b;
  uint2* orow = (uint2*)(o + (size_t)token * E_);
  #pragma unroll
  for (int i = 0; i < 4; ++i){
    float4 gg = gr[lane + 64 * i], bb = br[lane + 64 * i];
    float y0 = (v[i].x - mu) * rstd * gg.x + bb.x;
    float y1 = (v[i].y - mu) * rstd * gg.y + bb.y;
    float y2 = (v[i].z - mu) * rstd * gg.z + bb.z;
    float y3 = (v[i].w - mu) * rstd * gg.w + bb.w;
    orow[lane + 64 * i] = make_uint2(pack2(y0, y1), pack2(y2, y3));
  }
}

// ---------- weight prep: WqkvT[n][e] bf16, n = z*1024 + h*64 + d ----------
__global__ __launch_bounds__(256) void conv_qkv_kernel(
    const float* __restrict__ wk, const float* __restrict__ wq,
    const float* __restrict__ wv, u16* __restrict__ o)
{
  int n = blockIdx.x;                       // 0..3071
  int z = n >> 10, h = (n >> 6) & 15, d = n & 63;
  const float* w = (z == 0 ? wk : z == 1 ? wq : wv) + (size_t)h * (E_ * HD_) + d;
  int e0 = threadIdx.x << 2;
  float f0 = w[(size_t)(e0    ) * HD_];
  float f1 = w[(size_t)(e0 + 1) * HD_];
  float f2 = w[(size_t)(e0 + 2) * HD_];
  float f3 = w[(size_t)(e0 + 3) * HD_];
  *(uint2*)(o + (size_t)n * K_ + e0) = make_uint2(pack2(f0, f1), pack2(f2, f3));
}

// ---------- weight prep: Wt[n][k] = w[k][n] bf16 (transpose+cast) ----------
__global__ __launch_bounds__(256) void conv_t_kernel(
    const float* __restrict__ w, u16* __restrict__ o)
{
  int n = blockIdx.x;                       // 0..1023
  int k0 = threadIdx.x << 2;
  float f0 = w[(size_t)(k0    ) * E_ + n];
  float f1 = w[(size_t)(k0 + 1) * E_ + n];
  float f2 = w[(size_t)(k0 + 2) * E_ + n];
  float f3 = w[(size_t)(k0 + 3) * E_ + n];
  *(uint2*)(o + (size_t)n * K_ + k0) = make_uint2(pack2(f0, f1), pack2(f2, f3));
}

// ---------- MFMA GEMM: C(M x N) = A(M x 1024) * Bt(N x 1024)^T ----------
// 128x128 tile / 256 threads (4 waves in 2x2 of 64x64), BK=32, 16x16x32 bf16.
// MODE 0: qkv  -> k bf16 (Cb), q bf16 (Cb2), v fp32 (Cf), all (b,h,t,d)
// MODE 1: proj -> Cf fp32 = acc + bias + resid (x)        [row-major]
// MODE 2: ff1  -> Cb bf16 = relu(acc + bias)              [row-major]
// MODE 3: ff2  -> Cf fp32 = acc + bias + Cf (in-place residual)
template<int MODE>
__global__ __launch_bounds__(256) void mgemm_kernel(
    const u16* __restrict__ A, const u16* __restrict__ Bt,
    const float* __restrict__ bias, const float* __restrict__ resid,
    float* __restrict__ Cf, u16* __restrict__ Cb, u16* __restrict__ Cb2)
{
  __shared__ __align__(16) u16 As[128 * 32];   // [m][k] 8 KB
  __shared__ __align__(16) u16 Bs[128 * 32];   // [n][k] 8 KB
  const int row0 = blockIdx.x * 128, col0 = blockIdx.y * 128;
  const int tid = threadIdx.x, lane = tid & 63;
  const int wv_ = tid >> 6, wm = wv_ >> 1, wn = wv_ & 1;
  const int l15 = lane & 15, quad = lane >> 4;

  // staging: thread covers (row sr, k-bytes sk*2..), 16 B per gload16
  const int sr = tid >> 2, sk = (tid & 3) << 3;
  const u16* Ag0 = A  + (size_t)(row0 + sr) * K_ + sk;
  const u16* Ag1 = Ag0 + (size_t)64 * K_;
  const u16* Bg0 = Bt + (size_t)(col0 + sr) * K_ + sk;
  const u16* Bg1 = Bg0 + (size_t)64 * K_;
  u16* Al0 = As + tid * 8;           // bytes tid*16
  u16* Al1 = As + 2048 + tid * 8;
  u16* Bl0 = Bs + tid * 8;
  u16* Bl1 = Bs + 2048 + tid * 8;

  f32x4 acc[4][4];
  #pragma unroll
  for (int i = 0; i < 4; ++i)
    #pragma unroll
    for (int j = 0; j < 4; ++j)
      acc[i][j] = (f32x4){0.f, 0.f, 0.f, 0.f};

  for (int k0 = 0; k0 < K_; k0 += 32) {
    __syncthreads();                 // prev tile fully consumed
    gload16(Ag0 + k0, Al0);
    gload16(Ag1 + k0, Al1);
    gload16(Bg0 + k0, Bl0);
    gload16(Bg1 + k0, Bl1);
    __syncthreads();                 // compiler drains vmcnt before barrier

    bf16x8 a[4], b[4];
    #pragma unroll
    for (int i = 0; i < 4; ++i){
      a[i] = *(const bf16x8*)(As + (wm * 64 + i * 16 + l15) * 32 + quad * 8);
      b[i] = *(const bf16x8*)(Bs + (wn * 64 + i * 16 + l15) * 32 + quad * 8);
    }
    #pragma unroll
    for (int i = 0; i < 4; ++i)
      #pragma unroll
      for (int j = 0; j < 4; ++j)
        acc[i][j] = __builtin_amdgcn_mfma_f32_16x16x32_bf16(a[i], b[j], acc[i][j], 0, 0, 0);
  }

  // epilogue: lane holds D[quad*4 + r][l15] of each 16x16 tile
  #pragma unroll
  for (int j = 0; j < 4; ++j) {
    const int n = col0 + wn * 64 + j * 16 + l15;
    float bn = (MODE != 0 && bias) ? bias[n] : 0.f;
    #pragma unroll
    for (int i = 0; i < 4; ++i) {
      #pragma unroll
      for (int r = 0; r < 4; ++r) {
        const int row = row0 + wm * 64 + i * 16 + quad * 4 + r;
        float v = acc[i][j][r];
        if (MODE == 0) {
          int z = n >> 10, h = (n >> 6) & 15, d = n & 63;
          int bb = row >> 8, t = row & 255;
          size_t idx = ((size_t)(bb * H_ + h) * T_ + t) * HD_ + d;
          if (z == 0)      Cb [idx] = f2bf(v);
          else if (z == 1) Cb2[idx] = f2bf(v);
          else             Cf [idx] = v;
        } else if (MODE == 1) {
          size_t idx = (size_t)row * E_ + n;
          Cf[idx] = v + bn + resid[idx];
        } else if (MODE == 2) {
          size_t idx = (size_t)row * E_ + n;
          Cb[idx] = f2bf(fmaxf(v + bn, 0.f));
        } else {
          size_t idx = (size_t)row * E_ + n;
          Cf[idx] = v + bn + Cf[idx];
        }
      }
    }
  }
}

// ---------- fused causal attention, one block per (b,h) ----------
// k,q bf16 (b,h,t,d); v fp32 (b,h,t,d, in d_out); out bf16 row-major (b,t,h*64+d)
// scores[t][s] = k_t . q_s / 8 (K.Q^T per reference), s <= t
__global__ __launch_bounds__(256) void attn_kernel(
    const u16* __restrict__ kk_, const u16* __restrict__ qq_,
    const float* __restrict__ vv_, u16* __restrict__ out)
{
  __shared__ __align__(16) float Vb[T_ * HD_];   // 64 KB
  __shared__ __align__(16) u16   Qb[64 * HD_];   // 8 KB
  const int bh = blockIdx.x;
  const int tid = threadIdx.x, t = tid;
  const u16*   kb = kk_ + (size_t)bh * (T_ * HD_);
  const u16*   qb = qq_ + (size_t)bh * (T_ * HD_);
  const float* vb = vv_ + (size_t)bh * (T_ * HD_);

  { const float4* s = (const float4*)vb; float4* d = (float4*)Vb;
    #pragma unroll
    for (int i = 0; i < 16; ++i) d[tid + 256 * i] = s[tid + 256 * i]; }

  float kreg[64];
  { const uint4* s = (const uint4*)(kb + (size_t)t * HD_);
    #pragma unroll
    for (int i = 0; i < 8; ++i){
      uint4 u = s[i];
      kreg[8*i  ]=bflo(u.x); kreg[8*i+1]=bfhi(u.x);
      kreg[8*i+2]=bflo(u.y); kreg[8*i+3]=bfhi(u.y);
      kreg[8*i+4]=bflo(u.z); kreg[8*i+5]=bfhi(u.z);
      kreg[8*i+6]=bflo(u.w); kreg[8*i+7]=bfhi(u.w);
    } }

  // pass A: running max + sumexp
  float m = -1e30f, l = 0.f;
  for (int st = 0; st < 4; ++st) {
    __syncthreads();
    { const uint4* s = (const uint4*)(qb + (size_t)st * 64 * HD_); uint4* d = (uint4*)Qb;
      d[tid] = s[tid]; d[tid + 256] = s[tid + 256]; }
    __syncthreads();
    int sEnd = min(63, t - st * 64);
    for (int sl = 0; sl <= sEnd; ++sl) {
      const u32* qr = (const u32*)(Qb + sl * HD_);
      float dot = 0.f;
      #pragma unroll
      for (int j = 0; j < 32; ++j) {
        u32 uq = qr[j];
        dot = fmaf(kreg[2*j], bflo(uq), dot);
        dot = fmaf(kreg[2*j+1], bfhi(uq), dot);
      }
      float sc = dot * 0.125f;
      float mn = fmaxf(m, sc);
      l = l * __expf(m - mn) + __expf(sc - mn);
      m = mn;
    }
  }

  // pass B: recompute, accumulate P @ V
  float acc[64];
  #pragma unroll
  for (int j = 0; j < 64; ++j) acc[j] = 0.f;
  for (int st = 0; st < 4; ++st) {
    __syncthreads();
    { const uint4* s = (const uint4*)(qb + (size_t)st * 64 * HD_); uint4* d = (uint4*)Qb;
      d[tid] = s[tid]; d[tid + 256] = s[tid + 256]; }
    __syncthreads();
    int sEnd = min(63, t - st * 64);
    for (int sl = 0; sl <= sEnd; ++sl) {
      const u32* qr = (const u32*)(Qb + sl * HD_);
      float dot = 0.f;
      #pragma unroll
      for (int j = 0; j < 32; ++j) {
        u32 uq = qr[j];
        dot = fmaf(kreg[2*j], bflo(uq), dot);
        dot = fmaf(kreg[2*j+1], bfhi(uq), dot);
      }
      float p = __expf(dot * 0.125f - m);
      const float* vr = Vb + (st * 64 + sl) * HD_;
      #pragma unroll
      for (int j = 0; j < 64; ++j) acc[j] = fmaf(p, vr[j], acc[j]);
    }
  }

  float inv = 1.0f / l;
  int bb = bh >> 4, h = bh & 15;
  u16* op = out + ((size_t)(bb * T_ + t)) * E_ + h * HD_;
  uint4* o4 = (uint4*)op;
  #pragma unroll
  for (int i = 0; i < 8; ++i)
    o4[i] = make_uint4(pack2(acc[8*i  ]*inv, acc[8*i+1]*inv),
                       pack2(acc[8*i+2]*inv, acc[8*i+3]*inv),
                       pack2(acc[8*i+4]*inv, acc[8*i+5]*inv),
                       pack2(acc[8*i+6]*inv, acc[8*i+7]*inv));
}

// ---------- launch ----------
extern "C" void kernel_launch(void* const* d_in, const int* in_sizes, int n_in,
                              void* d_out, int out_size, void* d_ws, size_t ws_size,
                              hipStream_t stream) {
  const float* x     = (const float*)d_in[0];
  const float* ln1g  = (const float*)d_in[1];
  const float* ln1b  = (const float*)d_in[2];
  const float* wk    = (const float*)d_in[3];
  const float* wq    = (const float*)d_in[4];
  const float* wv    = (const float*)d_in[5];
  const float* wproj = (const float*)d_in[6];
  const float* bproj = (const float*)d_in[7];
  const float* ln2g  = (const float*)d_in[8];
  const float* ln2b  = (const float*)d_in[9];
  const float* w1    = (const float*)d_in[10];
  const float* b1    = (const float*)d_in[11];
  const float* w2    = (const float*)d_in[12];
  const float* b2    = (const float*)d_in[13];
  float* outp = (float*)d_out;

  // ws layout (total 112 MB <= proven 128 MB):
  //  [0,6M)    WqkvT bf16 [3072][1024]
  //  [6M,8M)   WprojT bf16 [1024][1024]
  //  [8M,10M)  W1T
  //  [10M,12M) W2T
  //  [16M,48M) hb bf16 (LN1 out) -> attn_out bf16
  //  [48M,80M) k bf16 (bhtd)     -> h2 bf16 (LN2 out)
  //  [80M,112M) q bf16 (bhtd)    -> ff1 bf16
  // d_out: v fp32 (bhtd) -> x1 fp32 (row-major) -> final out (in-place)
  char* ws = (char*)d_ws;
  const size_t MB = 1024 * 1024;
  u16* wqkvT  = (u16*)(ws);
  u16* wprojT = (u16*)(ws + 6 * MB);
  u16* w1T    = (u16*)(ws + 8 * MB);
  u16* w2T    = (u16*)(ws + 10 * MB);
  u16* hb     = (u16*)(ws + 16 * MB);   // then attn_out
  u16* kbuf   = (u16*)(ws + 48 * MB);   // then h2
  u16* qbuf   = (u16*)(ws + 80 * MB);   // then ff1

  // weight prep (bf16, N-major = B^T layout)
  conv_qkv_kernel<<<3 * E_, 256, 0, stream>>>(wk, wq, wv, wqkvT);
  conv_t_kernel<<<E_, 256, 0, stream>>>(wproj, wprojT);
  conv_t_kernel<<<E_, 256, 0, stream>>>(w1, w1T);
  conv_t_kernel<<<E_, 256, 0, stream>>>(w2, w2T);

  // 1) hb = LN1(x) bf16
  ln_bf16_kernel<<<NTOK/4, 256, 0, stream>>>(x, ln1g, ln1b, hb);
  // 2) k,q (bf16) + v (fp32, d_out) = hb @ WqkvT^T
  mgemm_kernel<0><<<dim3(NTOK/128, 3*E_/128), 256, 0, stream>>>(
      hb, wqkvT, nullptr, nullptr, outp, kbuf, qbuf);
  // 3) attn -> bf16 row-major into hb
  attn_kernel<<<B_*H_, 256, 0, stream>>>(kbuf, qbuf, outp, hb);
  // 4) x1 = x + attn @ wproj + bproj -> fp32 d_out (over dead v)
  mgemm_kernel<1><<<dim3(NTOK/128, E_/128), 256, 0, stream>>>(
      hb, wprojT, bproj, x, outp, nullptr, nullptr);
  // 5) h2 = LN2(x1) bf16 (over dead k)
  ln_bf16_kernel<<<NTOK/4, 256, 0, stream>>>(outp, ln2g, ln2b, kbuf);
  // 6) ff1 = relu(h2 @ w1 + b1) bf16 (over dead q)
  mgemm_kernel<2><<<dim3(NTOK/128, E_/128), 256, 0, stream>>>(
      kbuf, w1T, b1, nullptr, nullptr, qbuf, nullptr);
  // 7) out = x1 + ff1 @ w2 + b2, in-place over d_out
  mgemm_kernel<3><<<dim3(NTOK/128, E_/128), 256, 0, stream>>>(
      qbuf, w2T, b2, nullptr, outp, nullptr, nullptr);
}

// Round 5
// 671.497 us; speedup vs baseline: 5.0700x; 2.1876x over previous
//
#include <hip/hip_runtime.h>

typedef unsigned int u32;
typedef unsigned short u16;
typedef __attribute__((ext_vector_type(8))) short bf16x8;   // 8 bf16 in 4 VGPRs
typedef __attribute__((ext_vector_type(4))) float f32x4;

#define GLOBAL_AS __attribute__((address_space(1)))
#define LDS_AS    __attribute__((address_space(3)))

#define B_   64
#define T_   256
#define E_   1024
#define H_   16
#define HD_  64
#define NTOK (B_*T_)          // 16384
#define K_   1024
#define LNEPS 1e-5f

// ---------- bf16 helpers ----------
__device__ __forceinline__ float bflo(u32 u){ return __uint_as_float(u << 16); }
__device__ __forceinline__ float bfhi(u32 u){ return __uint_as_float(u & 0xffff0000u); }
__device__ __forceinline__ u16 f2bf(float f){            // round-to-nearest-even
  u32 x = __float_as_uint(f);
  u32 r = x + 0x7fffu + ((x >> 16) & 1u);
  return (u16)(r >> 16);
}
__device__ __forceinline__ u16 f2bf_trunc(float f){      // truncate (P probs only)
  return (u16)(__float_as_uint(f) >> 16);
}
__device__ __forceinline__ u32 pack2(float a, float b){
  return (u32)f2bf(a) | ((u32)f2bf(b) << 16);
}

// async global->LDS, 16 B per lane (dest = wave-uniform base + lane*16)
__device__ __forceinline__ void gload16(const u16* g, u16* l){
  __builtin_amdgcn_global_load_lds((const GLOBAL_AS void*)g, (LDS_AS void*)l, 16, 0, 0);
}

// ---------- fused LayerNorm fp32 -> bf16, one wave per token ----------
__global__ __launch_bounds__(256) void ln_bf16_kernel(
    const float* __restrict__ x, const float* __restrict__ g,
    const float* __restrict__ b, u16* __restrict__ o)
{
  int lane  = threadIdx.x & 63;
  int token = (blockIdx.x << 2) + (threadIdx.x >> 6);
  const float4* xr = (const float4*)(x + (size_t)token * E_);
  float4 v[4];
  float s = 0.f, ss = 0.f;
  #pragma unroll
  for (int i = 0; i < 4; ++i){
    v[i] = xr[lane + 64 * i];
    s += v[i].x + v[i].y + v[i].z + v[i].w;
    ss = fmaf(v[i].x, v[i].x, fmaf(v[i].y, v[i].y,
         fmaf(v[i].z, v[i].z, fmaf(v[i].w, v[i].w, ss))));
  }
  #pragma unroll
  for (int off = 32; off > 0; off >>= 1){
    s  += __shfl_xor(s,  off);
    ss += __shfl_xor(ss, off);
  }
  float mu   = s * (1.f / E_);
  float var  = ss * (1.f / E_) - mu * mu;
  float rstd = rsqrtf(var + LNEPS);
  const float4* gr = (const float4*)g;
  const float4* br = (const float4*)b;
  uint2* orow = (uint2*)(o + (size_t)token * E_);
  #pragma unroll
  for (int i = 0; i < 4; ++i){
    float4 gg = gr[lane + 64 * i], bb = br[lane + 64 * i];
    float y0 = (v[i].x - mu) * rstd * gg.x + bb.x;
    float y1 = (v[i].y - mu) * rstd * gg.y + bb.y;
    float y2 = (v[i].z - mu) * rstd * gg.z + bb.z;
    float y3 = (v[i].w - mu) * rstd * gg.w + bb.w;
    orow[lane + 64 * i] = make_uint2(pack2(y0, y1), pack2(y2, y3));
  }
}

// ---------- weight prep: WqkvT[n][e] bf16, n = z*1024 + h*64 + d ----------
__global__ __launch_bounds__(256) void conv_qkv_kernel(
    const float* __restrict__ wk, const float* __restrict__ wq,
    const float* __restrict__ wv, u16* __restrict__ o)
{
  int n = blockIdx.x;                       // 0..3071
  int z = n >> 10, h = (n >> 6) & 15, d = n & 63;
  const float* w = (z == 0 ? wk : z == 1 ? wq : wv) + (size_t)h * (E_ * HD_) + d;
  int e0 = threadIdx.x << 2;
  float f0 = w[(size_t)(e0    ) * HD_];
  float f1 = w[(size_t)(e0 + 1) * HD_];
  float f2 = w[(size_t)(e0 + 2) * HD_];
  float f3 = w[(size_t)(e0 + 3) * HD_];
  *(uint2*)(o + (size_t)n * K_ + e0) = make_uint2(pack2(f0, f1), pack2(f2, f3));
}

// ---------- weight prep: Wt[n][k] = w[k][n] bf16 (transpose+cast) ----------
__global__ __launch_bounds__(256) void conv_t_kernel(
    const float* __restrict__ w, u16* __restrict__ o)
{
  int n = blockIdx.x;                       // 0..1023
  int k0 = threadIdx.x << 2;
  float f0 = w[(size_t)(k0    ) * E_ + n];
  float f1 = w[(size_t)(k0 + 1) * E_ + n];
  float f2 = w[(size_t)(k0 + 2) * E_ + n];
  float f3 = w[(size_t)(k0 + 3) * E_ + n];
  *(uint2*)(o + (size_t)n * K_ + k0) = make_uint2(pack2(f0, f1), pack2(f2, f3));
}

// ---------- MFMA GEMM: C(M x N) = A(M x 1024) * Bt(N x 1024)^T ----------
// 128x128 tile / 256 threads (4 waves in 2x2 of 64x64), BK=32, 16x16x32 bf16.
// MODE 0: qkv -> k bf16 (Cb), q bf16 (Cb2) in (b,h,t,d); v bf16 TRANSPOSED (b,h,d,t) via Cf
// MODE 1: proj -> Cf fp32 = acc + bias + resid (x)        [row-major]
// MODE 2: ff1  -> Cb bf16 = relu(acc + bias)              [row-major]
// MODE 3: ff2  -> Cf fp32 = acc + bias + Cf (in-place residual)
template<int MODE>
__global__ __launch_bounds__(256) void mgemm_kernel(
    const u16* __restrict__ A, const u16* __restrict__ Bt,
    const float* __restrict__ bias, const float* __restrict__ resid,
    float* __restrict__ Cf, u16* __restrict__ Cb, u16* __restrict__ Cb2)
{
  __shared__ __align__(16) u16 As[128 * 32];   // [m][k] 8 KB
  __shared__ __align__(16) u16 Bs[128 * 32];   // [n][k] 8 KB
  const int row0 = blockIdx.x * 128, col0 = blockIdx.y * 128;
  const int tid = threadIdx.x, lane = tid & 63;
  const int wv_ = tid >> 6, wm = wv_ >> 1, wn = wv_ & 1;
  const int l15 = lane & 15, quad = lane >> 4;

  const int sr = tid >> 2, sk = (tid & 3) << 3;
  const u16* Ag0 = A  + (size_t)(row0 + sr) * K_ + sk;
  const u16* Ag1 = Ag0 + (size_t)64 * K_;
  const u16* Bg0 = Bt + (size_t)(col0 + sr) * K_ + sk;
  const u16* Bg1 = Bg0 + (size_t)64 * K_;
  u16* Al0 = As + tid * 8;
  u16* Al1 = As + 2048 + tid * 8;
  u16* Bl0 = Bs + tid * 8;
  u16* Bl1 = Bs + 2048 + tid * 8;

  f32x4 acc[4][4];
  #pragma unroll
  for (int i = 0; i < 4; ++i)
    #pragma unroll
    for (int j = 0; j < 4; ++j)
      acc[i][j] = (f32x4){0.f, 0.f, 0.f, 0.f};

  for (int k0 = 0; k0 < K_; k0 += 32) {
    __syncthreads();
    gload16(Ag0 + k0, Al0);
    gload16(Ag1 + k0, Al1);
    gload16(Bg0 + k0, Bl0);
    gload16(Bg1 + k0, Bl1);
    __syncthreads();

    bf16x8 a[4], b[4];
    #pragma unroll
    for (int i = 0; i < 4; ++i){
      a[i] = *(const bf16x8*)(As + (wm * 64 + i * 16 + l15) * 32 + quad * 8);
      b[i] = *(const bf16x8*)(Bs + (wn * 64 + i * 16 + l15) * 32 + quad * 8);
    }
    #pragma unroll
    for (int i = 0; i < 4; ++i)
      #pragma unroll
      for (int j = 0; j < 4; ++j)
        acc[i][j] = __builtin_amdgcn_mfma_f32_16x16x32_bf16(a[i], b[j], acc[i][j], 0, 0, 0);
  }

  #pragma unroll
  for (int j = 0; j < 4; ++j) {
    const int n = col0 + wn * 64 + j * 16 + l15;
    float bn = (MODE != 0 && bias) ? bias[n] : 0.f;
    #pragma unroll
    for (int i = 0; i < 4; ++i) {
      #pragma unroll
      for (int r = 0; r < 4; ++r) {
        const int row = row0 + wm * 64 + i * 16 + quad * 4 + r;
        float v = acc[i][j][r];
        if (MODE == 0) {
          int z = n >> 10, h = (n >> 6) & 15, d = n & 63;
          int bb = row >> 8, t = row & 255;
          if (z == 0) {
            Cb [((size_t)(bb * H_ + h) * T_ + t) * HD_ + d] = f2bf(v);
          } else if (z == 1) {
            Cb2[((size_t)(bb * H_ + h) * T_ + t) * HD_ + d] = f2bf(v);
          } else {
            // v stored TRANSPOSED: (b,h,d,t)
            ((u16*)Cf)[((size_t)(bb * H_ + h) * HD_ + d) * T_ + t] = f2bf(v);
          }
        } else if (MODE == 1) {
          size_t idx = (size_t)row * E_ + n;
          Cf[idx] = v + bn + resid[idx];
        } else if (MODE == 2) {
          size_t idx = (size_t)row * E_ + n;
          Cb[idx] = f2bf(fmaxf(v + bn, 0.f));
        } else {
          size_t idx = (size_t)row * E_ + n;
          Cf[idx] = v + bn + Cf[idx];
        }
      }
    }
  }
}

// ---------- MFMA flash attention: one block per (b,h), wave w owns t-block w ----------
// scores[t][s] = k_t . q_s / 8 (K.Q^T per reference), causal s<=t.
// k,q bf16 (b,h,t,d); vt bf16 (b,h,d,t); out bf16 row-major (b,t,h*64+d).
// Uniform barriers: all 4 waves run the fixed 4-iteration loop; compute guarded, barriers not.
__global__ __launch_bounds__(256) void fattn_kernel(
    const u16* __restrict__ kk_, const u16* __restrict__ qq_,
    const u16* __restrict__ vt_, u16* __restrict__ out)
{
  __shared__ __align__(16) u16 Pb[4][64 * 72];  // per-wave private, 9216 B each
  const int bh = blockIdx.x;
  const int tid = threadIdx.x, lane = tid & 63, wv = tid >> 6;   // wave wv owns tblk=wv
  const int l15 = lane & 15, quad = lane >> 4;
  const u16* kb  = kk_ + (size_t)bh * (T_ * HD_);
  const u16* qb  = qq_ + (size_t)bh * (T_ * HD_);
  const u16* vtb = vt_ + (size_t)bh * (HD_ * T_);
  u16* Pw = Pb[wv];

  // K fragments for this wave's t-block: A[m=t][k=d], lane holds A[l15][quad*8+j]
  bf16x8 kf[4][2];
  #pragma unroll
  for (int i = 0; i < 4; ++i)
    #pragma unroll
    for (int c = 0; c < 2; ++c)
      kf[i][c] = *(const bf16x8*)(kb + (size_t)(wv*64 + i*16 + l15) * HD_ + c*32 + quad*8);

  f32x4 o[4][4];                 // [t-tile i][d-tile jd], C-layout
  float mrow[4][4], lrow[4][4];  // [i][r], replicated across the 16 lanes of a quad
  #pragma unroll
  for (int i = 0; i < 4; ++i) {
    #pragma unroll
    for (int j = 0; j < 4; ++j) o[i][j] = (f32x4){0.f, 0.f, 0.f, 0.f};
    #pragma unroll
    for (int r = 0; r < 4; ++r) { mrow[i][r] = -1e30f; lrow[i][r] = 0.f; }
  }

  for (int sb = 0; sb < 4; ++sb) {          // FIXED trip count (uniform barriers)
    if (sb <= wv) {
      // ---- S = K . Q^T (4x4 tiles of 16x16, K-dim 64 = 2 chunks) ----
      f32x4 S[4][4];
      #pragma unroll
      for (int j = 0; j < 4; ++j) {
        bf16x8 qf0 = *(const bf16x8*)(qb + (size_t)(sb*64 + j*16 + l15) * HD_ +      quad*8);
        bf16x8 qf1 = *(const bf16x8*)(qb + (size_t)(sb*64 + j*16 + l15) * HD_ + 32 + quad*8);
        #pragma unroll
        for (int i = 0; i < 4; ++i) {
          f32x4 t0 = __builtin_amdgcn_mfma_f32_16x16x32_bf16(kf[i][0], qf0,
                         (f32x4){0.f,0.f,0.f,0.f}, 0, 0, 0);
          S[i][j] = __builtin_amdgcn_mfma_f32_16x16x32_bf16(kf[i][1], qf1, t0, 0, 0, 0);
        }
      }
      // ---- scale + causal mask (diagonal s-block only) ----
      #pragma unroll
      for (int i = 0; i < 4; ++i)
        #pragma unroll
        for (int j = 0; j < 4; ++j)
          #pragma unroll
          for (int r = 0; r < 4; ++r) {
            float val = S[i][j][r] * 0.125f;
            if (sb == wv) {
              int tl = i*16 + quad*4 + r, sl = j*16 + l15;
              if (sl > tl) val = -1e30f;
            }
            S[i][j][r] = val;
          }
      // ---- online softmax per row; P = exp(S - m_new); rescale O ----
      #pragma unroll
      for (int i = 0; i < 4; ++i)
        #pragma unroll
        for (int r = 0; r < 4; ++r) {
          float mx = fmaxf(fmaxf(S[i][0][r], S[i][1][r]), fmaxf(S[i][2][r], S[i][3][r]));
          #pragma unroll
          for (int msk = 1; msk < 16; msk <<= 1) mx = fmaxf(mx, __shfl_xor(mx, msk));
          float mn = fmaxf(mrow[i][r], mx);
          float al = __expf(mrow[i][r] - mn);
          mrow[i][r] = mn;
          float sm = 0.f;
          #pragma unroll
          for (int j = 0; j < 4; ++j) {
            float p = __expf(S[i][j][r] - mn);
            S[i][j][r] = p;
            sm += p;
          }
          #pragma unroll
          for (int msk = 1; msk < 16; msk <<= 1) sm += __shfl_xor(sm, msk);
          lrow[i][r] = lrow[i][r] * al + sm;
          #pragma unroll
          for (int jd = 0; jd < 4; ++jd) o[i][jd][r] *= al;
        }
      // ---- P (C-layout) -> private LDS [t][s], padded stride 72 ----
      #pragma unroll
      for (int i = 0; i < 4; ++i)
        #pragma unroll
        for (int j = 0; j < 4; ++j)
          #pragma unroll
          for (int r = 0; r < 4; ++r)
            Pw[(i*16 + quad*4 + r) * 72 + j*16 + l15] = f2bf_trunc(S[i][j][r]);
    }
    __syncthreads();                        // uniform: all 4 waves
    if (sb <= wv) {
      // ---- O += P . V  (P as A-frag from LDS; V^T as B-frag from global) ----
      bf16x8 pf[4][2];
      #pragma unroll
      for (int i = 0; i < 4; ++i)
        #pragma unroll
        for (int c = 0; c < 2; ++c)
          pf[i][c] = *(const bf16x8*)(Pw + (i*16 + l15) * 72 + c*32 + quad*8);
      #pragma unroll
      for (int jd = 0; jd < 4; ++jd) {
        bf16x8 vf0 = *(const bf16x8*)(vtb + (size_t)(jd*16 + l15) * T_ + sb*64 +      quad*8);
        bf16x8 vf1 = *(const bf16x8*)(vtb + (size_t)(jd*16 + l15) * T_ + sb*64 + 32 + quad*8);
        #pragma unroll
        for (int i = 0; i < 4; ++i) {
          f32x4 t0 = __builtin_amdgcn_mfma_f32_16x16x32_bf16(pf[i][0], vf0, o[i][jd], 0, 0, 0);
          o[i][jd] = __builtin_amdgcn_mfma_f32_16x16x32_bf16(pf[i][1], vf1, t0, 0, 0, 0);
        }
      }
    }
    __syncthreads();                        // uniform: protect next iter's P writes
  }

  // ---- normalize, transpose via private LDS, coalesced bf16 store ----
  #pragma unroll
  for (int i = 0; i < 4; ++i)
    #pragma unroll
    for (int r = 0; r < 4; ++r) {
      float inv = 1.0f / lrow[i][r];
      #pragma unroll
      for (int jd = 0; jd < 4; ++jd)
        Pw[(i*16 + quad*4 + r) * 72 + jd*16 + l15] = f2bf(o[i][jd][r] * inv);
    }
  __syncthreads();                          // uniform
  {
    const int b = bh >> 4, h = bh & 15;
    const uint4* pr = (const uint4*)(Pw + lane * 72);
    uint4* og = (uint4*)(out + ((size_t)(b * T_ + wv*64 + lane)) * E_ + h * HD_);
    #pragma unroll
    for (int k = 0; k < 8; ++k) og[k] = pr[k];
  }
}

// ---------- launch ----------
extern "C" void kernel_launch(void* const* d_in, const int* in_sizes, int n_in,
                              void* d_out, int out_size, void* d_ws, size_t ws_size,
                              hipStream_t stream) {
  const float* x     = (const float*)d_in[0];
  const float* ln1g  = (const float*)d_in[1];
  const float* ln1b  = (const float*)d_in[2];
  const float* wk    = (const float*)d_in[3];
  const float* wq    = (const float*)d_in[4];
  const float* wv    = (const float*)d_in[5];
  const float* wproj = (const float*)d_in[6];
  const float* bproj = (const float*)d_in[7];
  const float* ln2g  = (const float*)d_in[8];
  const float* ln2b  = (const float*)d_in[9];
  const float* w1    = (const float*)d_in[10];
  const float* b1    = (const float*)d_in[11];
  const float* w2    = (const float*)d_in[12];
  const float* b2    = (const float*)d_in[13];
  float* outp = (float*)d_out;

  // ws (112 MB <= proven 128 MB):
  //  [0,6M) WqkvT | [6,8M) WprojT | [8,10M) W1T | [10,12M) W2T
  //  [16,48M) hb bf16 (LN1 out -> attn out)
  //  [48,80M) k bf16 (bhtd) -> h2 bf16 | [80,112M) q bf16 (bhtd) -> ff1 bf16
  // d_out (64MB): v^T bf16 (b,h,d,t) [0,32M) -> x1 fp32 (full) -> out (in-place)
  char* ws = (char*)d_ws;
  const size_t MB = 1024 * 1024;
  u16* wqkvT  = (u16*)(ws);
  u16* wprojT = (u16*)(ws + 6 * MB);
  u16* w1T    = (u16*)(ws + 8 * MB);
  u16* w2T    = (u16*)(ws + 10 * MB);
  u16* hb     = (u16*)(ws + 16 * MB);
  u16* kbuf   = (u16*)(ws + 48 * MB);
  u16* qbuf   = (u16*)(ws + 80 * MB);
  u16* vtbuf  = (u16*)d_out;                   // v^T (b,h,d,t) bf16

  conv_qkv_kernel<<<3 * E_, 256, 0, stream>>>(wk, wq, wv, wqkvT);
  conv_t_kernel<<<E_, 256, 0, stream>>>(wproj, wprojT);
  conv_t_kernel<<<E_, 256, 0, stream>>>(w1, w1T);
  conv_t_kernel<<<E_, 256, 0, stream>>>(w2, w2T);

  // 1) hb = LN1(x) bf16
  ln_bf16_kernel<<<NTOK/4, 256, 0, stream>>>(x, ln1g, ln1b, hb);
  // 2) k,q bf16 (bhtd) + v^T bf16 (bhdt, d_out) = hb @ WqkvT^T
  mgemm_kernel<0><<<dim3(NTOK/128, 3*E_/128), 256, 0, stream>>>(
      hb, wqkvT, nullptr, nullptr, (float*)vtbuf, kbuf, qbuf);
  // 3) MFMA flash attention -> bf16 row-major into hb
  fattn_kernel<<<B_*H_, 256, 0, stream>>>(kbuf, qbuf, vtbuf, hb);
  // 4) x1 = x + attn @ wproj + bproj -> fp32 d_out (v^T dead)
  mgemm_kernel<1><<<dim3(NTOK/128, E_/128), 256, 0, stream>>>(
      hb, wprojT, bproj, x, outp, nullptr, nullptr);
  // 5) h2 = LN2(x1) bf16 (over dead k)
  ln_bf16_kernel<<<NTOK/4, 256, 0, stream>>>(outp, ln2g, ln2b, kbuf);
  // 6) ff1 = relu(h2 @ w1 + b1) bf16 (over dead q)
  mgemm_kernel<2><<<dim3(NTOK/128, E_/128), 256, 0, stream>>>(
      kbuf, w1T, b1, nullptr, nullptr, qbuf, nullptr);
  // 7) out = x1 + ff1 @ w2 + b2, in-place over d_out
  mgemm_kernel<3><<<dim3(NTOK/128, E_/128), 256, 0, stream>>>(
      qbuf, w2T, b2, nullptr, outp, nullptr, nullptr);
}

// Round 6
// 629.814 us; speedup vs baseline: 5.4055x; 1.0662x over previous
//
#include <hip/hip_runtime.h>

typedef unsigned int u32;
typedef unsigned short u16;
typedef __attribute__((ext_vector_type(8))) short bf16x8;   // 8 bf16 in 4 VGPRs
typedef __attribute__((ext_vector_type(4))) float f32x4;

#define GLOBAL_AS __attribute__((address_space(1)))
#define LDS_AS    __attribute__((address_space(3)))

#define B_   64
#define T_   256
#define E_   1024
#define H_   16
#define HD_  64
#define NTOK (B_*T_)          // 16384
#define K_   1024
#define LNEPS 1e-5f

// ---------- bf16 helpers ----------
__device__ __forceinline__ float bflo(u32 u){ return __uint_as_float(u << 16); }
__device__ __forceinline__ float bfhi(u32 u){ return __uint_as_float(u & 0xffff0000u); }
__device__ __forceinline__ u16 f2bf(float f){            // round-to-nearest-even
  u32 x = __float_as_uint(f);
  u32 r = x + 0x7fffu + ((x >> 16) & 1u);
  return (u16)(r >> 16);
}
__device__ __forceinline__ u16 f2bf_trunc(float f){      // truncate (P probs only)
  return (u16)(__float_as_uint(f) >> 16);
}
__device__ __forceinline__ u32 pack2(float a, float b){
  return (u32)f2bf(a) | ((u32)f2bf(b) << 16);
}

// async global->LDS, 16 B per lane (dest = wave-uniform base + lane*16)
__device__ __forceinline__ void gload16(const u16* g, u16* l){
  __builtin_amdgcn_global_load_lds((const GLOBAL_AS void*)g, (LDS_AS void*)l, 16, 0, 0);
}

// ---------- fused LayerNorm fp32 -> bf16, one wave per token ----------
__global__ __launch_bounds__(256) void ln_bf16_kernel(
    const float* __restrict__ x, const float* __restrict__ g,
    const float* __restrict__ b, u16* __restrict__ o)
{
  int lane  = threadIdx.x & 63;
  int token = (blockIdx.x << 2) + (threadIdx.x >> 6);
  const float4* xr = (const float4*)(x + (size_t)token * E_);
  float4 v[4];
  float s = 0.f, ss = 0.f;
  #pragma unroll
  for (int i = 0; i < 4; ++i){
    v[i] = xr[lane + 64 * i];
    s += v[i].x + v[i].y + v[i].z + v[i].w;
    ss = fmaf(v[i].x, v[i].x, fmaf(v[i].y, v[i].y,
         fmaf(v[i].z, v[i].z, fmaf(v[i].w, v[i].w, ss))));
  }
  #pragma unroll
  for (int off = 32; off > 0; off >>= 1){
    s  += __shfl_xor(s,  off);
    ss += __shfl_xor(ss, off);
  }
  float mu   = s * (1.f / E_);
  float var  = ss * (1.f / E_) - mu * mu;
  float rstd = rsqrtf(var + LNEPS);
  const float4* gr = (const float4*)g;
  const float4* br = (const float4*)b;
  uint2* orow = (uint2*)(o + (size_t)token * E_);
  #pragma unroll
  for (int i = 0; i < 4; ++i){
    float4 gg = gr[lane + 64 * i], bb = br[lane + 64 * i];
    float y0 = (v[i].x - mu) * rstd * gg.x + bb.x;
    float y1 = (v[i].y - mu) * rstd * gg.y + bb.y;
    float y2 = (v[i].z - mu) * rstd * gg.z + bb.z;
    float y3 = (v[i].w - mu) * rstd * gg.w + bb.w;
    orow[lane + 64 * i] = make_uint2(pack2(y0, y1), pack2(y2, y3));
  }
}

// ---------- weight prep (coalesced, LDS transpose) ----------
// qkv: out[n][e] bf16, n = z*1024 + h*64 + d, from w_z[h][e][d] fp32.
// grid (48, 16): blockIdx.x = z*16+h, blockIdx.y = 64-wide e-tile.
__global__ __launch_bounds__(256) void convq_kernel(
    const float* __restrict__ wk, const float* __restrict__ wq,
    const float* __restrict__ wv, u16* __restrict__ o)
{
  __shared__ float tile[64 * 68];
  const int zh = blockIdx.x, z = zh >> 4, h = zh & 15;
  const int e0 = blockIdx.y << 6;
  const float* w = (z == 0 ? wk : z == 1 ? wq : wv) + (size_t)h * (E_ * HD_);
  const int t = threadIdx.x;
  {
    int er = t >> 2, d0 = (t & 3) << 4;     // 16 floats per thread, coalesced rows
    const float4* src = (const float4*)(w + (size_t)(e0 + er) * HD_ + d0);
    #pragma unroll
    for (int i = 0; i < 4; ++i)
      *(float4*)(tile + er * 68 + d0 + 4 * i) = src[i];
  }
  __syncthreads();
  {
    int dr = t >> 2, ee = (t & 3) << 4;
    u32 wd[8];
    #pragma unroll
    for (int j = 0; j < 8; ++j)
      wd[j] = pack2(tile[(ee + 2*j) * 68 + dr], tile[(ee + 2*j + 1) * 68 + dr]);
    u16* dst = o + (size_t)(z * 1024 + h * 64 + dr) * K_ + e0 + ee;
    *(uint4*)(dst    ) = make_uint4(wd[0], wd[1], wd[2], wd[3]);
    *(uint4*)(dst + 8) = make_uint4(wd[4], wd[5], wd[6], wd[7]);
  }
}

// square: out[n][k] bf16 = w[k][n] fp32. grid (16, 16): n-tile, k-tile.
__global__ __launch_bounds__(256) void convt_kernel(
    const float* __restrict__ w, u16* __restrict__ o)
{
  __shared__ float tile[64 * 68];
  const int n0 = blockIdx.x << 6, k0 = blockIdx.y << 6;
  const int t = threadIdx.x;
  {
    int kr = t >> 2, nn = (t & 3) << 4;
    const float4* src = (const float4*)(w + (size_t)(k0 + kr) * E_ + n0 + nn);
    #pragma unroll
    for (int i = 0; i < 4; ++i)
      *(float4*)(tile + kr * 68 + nn + 4 * i) = src[i];
  }
  __syncthreads();
  {
    int nr = t >> 2, kk = (t & 3) << 4;
    u32 wd[8];
    #pragma unroll
    for (int j = 0; j < 8; ++j)
      wd[j] = pack2(tile[(kk + 2*j) * 68 + nr], tile[(kk + 2*j + 1) * 68 + nr]);
    u16* dst = o + (size_t)(n0 + nr) * K_ + k0 + kk;
    *(uint4*)(dst    ) = make_uint4(wd[0], wd[1], wd[2], wd[3]);
    *(uint4*)(dst + 8) = make_uint4(wd[4], wd[5], wd[6], wd[7]);
  }
}

// ---------- MFMA GEMM: C(M x N) = A(M x 1024) * Bt(N x 1024)^T ----------
// 128x128 tile / 256 threads (4 waves in 2x2 of 64x64), BK=32, 16x16x32 bf16.
// LDS is XOR-swizzled on the 16-B chunk axis: slot(m, q) = 4m + (q ^ ((m>>1)&3)),
// making frag ds_read_b128s 2-way (free) instead of 8-way bank-conflicted.
// MODE 0: qkv -> k bf16 (Cb), q bf16 (Cb2) in (b,h,t,d); v bf16 TRANSPOSED (b,h,d,t) via Cf
// MODE 1: proj -> Cf fp32 = acc + bias + resid (x)        [row-major]
// MODE 2: ff1  -> Cb bf16 = relu(acc + bias)              [row-major]
// MODE 3: ff2  -> Cf fp32 = acc + bias + Cf (in-place residual)
template<int MODE>
__global__ __launch_bounds__(256) void mgemm_kernel(
    const u16* __restrict__ A, const u16* __restrict__ Bt,
    const float* __restrict__ bias, const float* __restrict__ resid,
    float* __restrict__ Cf, u16* __restrict__ Cb, u16* __restrict__ Cb2)
{
  __shared__ __align__(16) u16 As[128 * 32];   // [m][k] 8 KB (chunk-swizzled)
  __shared__ __align__(16) u16 Bs[128 * 32];   // [n][k] 8 KB (chunk-swizzled)
  const int row0 = blockIdx.x * 128, col0 = blockIdx.y * 128;
  const int tid = threadIdx.x, lane = tid & 63;
  const int wv_ = tid >> 6, wm = wv_ >> 1, wn = wv_ & 1;
  const int l15 = lane & 15, quad = lane >> 4;

  // staging: lane's LDS slot is fixed (tid*16 B); fetch the swizzled source chunk
  const int sr = tid >> 2;
  const int sc = ((tid & 3) ^ ((tid >> 3) & 3)) << 3;   // swizzled k-elem offset
  const u16* Ag0 = A  + (size_t)(row0 + sr) * K_ + sc;
  const u16* Ag1 = Ag0 + (size_t)64 * K_;
  const u16* Bg0 = Bt + (size_t)(col0 + sr) * K_ + sc;
  const u16* Bg1 = Bg0 + (size_t)64 * K_;
  u16* Al0 = As + tid * 8;
  u16* Al1 = As + 2048 + tid * 8;
  u16* Bl0 = Bs + tid * 8;
  u16* Bl1 = Bs + 2048 + tid * 8;

  // frag-read swizzle: chunk = quad ^ ((m>>1)&3); (m>>1)&3 == (l15>>1)&3 (i*16 ≡ 0 mod 4)
  const int sq = (quad ^ ((l15 >> 1) & 3)) << 3;

  f32x4 acc[4][4];
  #pragma unroll
  for (int i = 0; i < 4; ++i)
    #pragma unroll
    for (int j = 0; j < 4; ++j)
      acc[i][j] = (f32x4){0.f, 0.f, 0.f, 0.f};

  for (int k0 = 0; k0 < K_; k0 += 32) {
    __syncthreads();
    gload16(Ag0 + k0, Al0);
    gload16(Ag1 + k0, Al1);
    gload16(Bg0 + k0, Bl0);
    gload16(Bg1 + k0, Bl1);
    __syncthreads();

    bf16x8 a[4], b[4];
    #pragma unroll
    for (int i = 0; i < 4; ++i){
      a[i] = *(const bf16x8*)(As + (wm * 64 + i * 16 + l15) * 32 + sq);
      b[i] = *(const bf16x8*)(Bs + (wn * 64 + i * 16 + l15) * 32 + sq);
    }
    #pragma unroll
    for (int i = 0; i < 4; ++i)
      #pragma unroll
      for (int j = 0; j < 4; ++j)
        acc[i][j] = __builtin_amdgcn_mfma_f32_16x16x32_bf16(a[i], b[j], acc[i][j], 0, 0, 0);
  }

  #pragma unroll
  for (int j = 0; j < 4; ++j) {
    const int n = col0 + wn * 64 + j * 16 + l15;
    float bn = (MODE != 0 && bias) ? bias[n] : 0.f;
    #pragma unroll
    for (int i = 0; i < 4; ++i) {
      #pragma unroll
      for (int r = 0; r < 4; ++r) {
        const int row = row0 + wm * 64 + i * 16 + quad * 4 + r;
        float v = acc[i][j][r];
        if (MODE == 0) {
          int z = n >> 10, h = (n >> 6) & 15, d = n & 63;
          int bb = row >> 8, t = row & 255;
          if (z == 0) {
            Cb [((size_t)(bb * H_ + h) * T_ + t) * HD_ + d] = f2bf(v);
          } else if (z == 1) {
            Cb2[((size_t)(bb * H_ + h) * T_ + t) * HD_ + d] = f2bf(v);
          } else {
            // v stored TRANSPOSED: (b,h,d,t)
            ((u16*)Cf)[((size_t)(bb * H_ + h) * HD_ + d) * T_ + t] = f2bf(v);
          }
        } else if (MODE == 1) {
          size_t idx = (size_t)row * E_ + n;
          Cf[idx] = v + bn + resid[idx];
        } else if (MODE == 2) {
          size_t idx = (size_t)row * E_ + n;
          Cb[idx] = f2bf(fmaxf(v + bn, 0.f));
        } else {
          size_t idx = (size_t)row * E_ + n;
          Cf[idx] = v + bn + Cf[idx];
        }
      }
    }
  }
}

// ---------- MFMA flash attention: one block per (b,h), wave w owns t-block w ----------
// scores[t][s] = k_t . q_s / 8 (K.Q^T per reference), causal s<=t.
// k,q bf16 (b,h,t,d); vt bf16 (b,h,d,t); out bf16 row-major (b,t,h*64+d).
// Uniform barriers: all 4 waves run the fixed 4-iteration loop; compute guarded, barriers not.
__global__ __launch_bounds__(256) void fattn_kernel(
    const u16* __restrict__ kk_, const u16* __restrict__ qq_,
    const u16* __restrict__ vt_, u16* __restrict__ out)
{
  __shared__ __align__(16) u16 Pb[4][64 * 72];  // per-wave private, 9216 B each
  const int bh = blockIdx.x;
  const int tid = threadIdx.x, lane = tid & 63, wv = tid >> 6;   // wave wv owns tblk=wv
  const int l15 = lane & 15, quad = lane >> 4;
  const u16* kb  = kk_ + (size_t)bh * (T_ * HD_);
  const u16* qb  = qq_ + (size_t)bh * (T_ * HD_);
  const u16* vtb = vt_ + (size_t)bh * (HD_ * T_);
  u16* Pw = Pb[wv];

  // K fragments for this wave's t-block: A[m=t][k=d], lane holds A[l15][quad*8+j]
  bf16x8 kf[4][2];
  #pragma unroll
  for (int i = 0; i < 4; ++i)
    #pragma unroll
    for (int c = 0; c < 2; ++c)
      kf[i][c] = *(const bf16x8*)(kb + (size_t)(wv*64 + i*16 + l15) * HD_ + c*32 + quad*8);

  f32x4 o[4][4];                 // [t-tile i][d-tile jd], C-layout
  float mrow[4][4], lrow[4][4];  // [i][r], replicated across the 16 lanes of a quad
  #pragma unroll
  for (int i = 0; i < 4; ++i) {
    #pragma unroll
    for (int j = 0; j < 4; ++j) o[i][j] = (f32x4){0.f, 0.f, 0.f, 0.f};
    #pragma unroll
    for (int r = 0; r < 4; ++r) { mrow[i][r] = -1e30f; lrow[i][r] = 0.f; }
  }

  for (int sb = 0; sb < 4; ++sb) {          // FIXED trip count (uniform barriers)
    if (sb <= wv) {
      // ---- S = K . Q^T (4x4 tiles of 16x16, K-dim 64 = 2 chunks) ----
      f32x4 S[4][4];
      #pragma unroll
      for (int j = 0; j < 4; ++j) {
        bf16x8 qf0 = *(const bf16x8*)(qb + (size_t)(sb*64 + j*16 + l15) * HD_ +      quad*8);
        bf16x8 qf1 = *(const bf16x8*)(qb + (size_t)(sb*64 + j*16 + l15) * HD_ + 32 + quad*8);
        #pragma unroll
        for (int i = 0; i < 4; ++i) {
          f32x4 t0 = __builtin_amdgcn_mfma_f32_16x16x32_bf16(kf[i][0], qf0,
                         (f32x4){0.f,0.f,0.f,0.f}, 0, 0, 0);
          S[i][j] = __builtin_amdgcn_mfma_f32_16x16x32_bf16(kf[i][1], qf1, t0, 0, 0, 0);
        }
      }
      // ---- scale + causal mask (diagonal s-block only) ----
      #pragma unroll
      for (int i = 0; i < 4; ++i)
        #pragma unroll
        for (int j = 0; j < 4; ++j)
          #pragma unroll
          for (int r = 0; r < 4; ++r) {
            float val = S[i][j][r] * 0.125f;
            if (sb == wv) {
              int tl = i*16 + quad*4 + r, sl = j*16 + l15;
              if (sl > tl) val = -1e30f;
            }
            S[i][j][r] = val;
          }
      // ---- online softmax per row; P = exp(S - m_new); rescale O ----
      #pragma unroll
      for (int i = 0; i < 4; ++i)
        #pragma unroll
        for (int r = 0; r < 4; ++r) {
          float mx = fmaxf(fmaxf(S[i][0][r], S[i][1][r]), fmaxf(S[i][2][r], S[i][3][r]));
          #pragma unroll
          for (int msk = 1; msk < 16; msk <<= 1) mx = fmaxf(mx, __shfl_xor(mx, msk));
          float mn = fmaxf(mrow[i][r], mx);
          float al = __expf(mrow[i][r] - mn);
          mrow[i][r] = mn;
          float sm = 0.f;
          #pragma unroll
          for (int j = 0; j < 4; ++j) {
            float p = __expf(S[i][j][r] - mn);
            S[i][j][r] = p;
            sm += p;
          }
          #pragma unroll
          for (int msk = 1; msk < 16; msk <<= 1) sm += __shfl_xor(sm, msk);
          lrow[i][r] = lrow[i][r] * al + sm;
          #pragma unroll
          for (int jd = 0; jd < 4; ++jd) o[i][jd][r] *= al;
        }
      // ---- P (C-layout) -> private LDS [t][s], padded stride 72 ----
      #pragma unroll
      for (int i = 0; i < 4; ++i)
        #pragma unroll
        for (int j = 0; j < 4; ++j)
          #pragma unroll
          for (int r = 0; r < 4; ++r)
            Pw[(i*16 + quad*4 + r) * 72 + j*16 + l15] = f2bf_trunc(S[i][j][r]);
    }
    __syncthreads();                        // uniform: all 4 waves
    if (sb <= wv) {
      // ---- O += P . V  (P as A-frag from LDS; V^T as B-frag from global) ----
      bf16x8 pf[4][2];
      #pragma unroll
      for (int i = 0; i < 4; ++i)
        #pragma unroll
        for (int c = 0; c < 2; ++c)
          pf[i][c] = *(const bf16x8*)(Pw + (i*16 + l15) * 72 + c*32 + quad*8);
      #pragma unroll
      for (int jd = 0; jd < 4; ++jd) {
        bf16x8 vf0 = *(const bf16x8*)(vtb + (size_t)(jd*16 + l15) * T_ + sb*64 +      quad*8);
        bf16x8 vf1 = *(const bf16x8*)(vtb + (size_t)(jd*16 + l15) * T_ + sb*64 + 32 + quad*8);
        #pragma unroll
        for (int i = 0; i < 4; ++i) {
          f32x4 t0 = __builtin_amdgcn_mfma_f32_16x16x32_bf16(pf[i][0], vf0, o[i][jd], 0, 0, 0);
          o[i][jd] = __builtin_amdgcn_mfma_f32_16x16x32_bf16(pf[i][1], vf1, t0, 0, 0, 0);
        }
      }
    }
    __syncthreads();                        // uniform: protect next iter's P writes
  }

  // ---- normalize, transpose via private LDS, coalesced bf16 store ----
  #pragma unroll
  for (int i = 0; i < 4; ++i)
    #pragma unroll
    for (int r = 0; r < 4; ++r) {
      float inv = 1.0f / lrow[i][r];
      #pragma unroll
      for (int jd = 0; jd < 4; ++jd)
        Pw[(i*16 + quad*4 + r) * 72 + jd*16 + l15] = f2bf(o[i][jd][r] * inv);
    }
  __syncthreads();                          // uniform
  {
    const int b = bh >> 4, h = bh & 15;
    const uint4* pr = (const uint4*)(Pw + lane * 72);
    uint4* og = (uint4*)(out + ((size_t)(b * T_ + wv*64 + lane)) * E_ + h * HD_);
    #pragma unroll
    for (int k = 0; k < 8; ++k) og[k] = pr[k];
  }
}

// ---------- launch ----------
extern "C" void kernel_launch(void* const* d_in, const int* in_sizes, int n_in,
                              void* d_out, int out_size, void* d_ws, size_t ws_size,
                              hipStream_t stream) {
  const float* x     = (const float*)d_in[0];
  const float* ln1g  = (const float*)d_in[1];
  const float* ln1b  = (const float*)d_in[2];
  const float* wk    = (const float*)d_in[3];
  const float* wq    = (const float*)d_in[4];
  const float* wv    = (const float*)d_in[5];
  const float* wproj = (const float*)d_in[6];
  const float* bproj = (const float*)d_in[7];
  const float* ln2g  = (const float*)d_in[8];
  const float* ln2b  = (const float*)d_in[9];
  const float* w1    = (const float*)d_in[10];
  const float* b1    = (const float*)d_in[11];
  const float* w2    = (const float*)d_in[12];
  const float* b2    = (const float*)d_in[13];
  float* outp = (float*)d_out;

  // ws (112 MB <= proven 128 MB):
  //  [0,6M) WqkvT | [6,8M) WprojT | [8,10M) W1T | [10,12M) W2T
  //  [16,48M) hb bf16 (LN1 out -> attn out)
  //  [48,80M) k bf16 (bhtd) -> h2 bf16 | [80,112M) q bf16 (bhtd) -> ff1 bf16
  // d_out (64MB): v^T bf16 (b,h,d,t) [0,32M) -> x1 fp32 (full) -> out (in-place)
  char* ws = (char*)d_ws;
  const size_t MB = 1024 * 1024;
  u16* wqkvT  = (u16*)(ws);
  u16* wprojT = (u16*)(ws + 6 * MB);
  u16* w1T    = (u16*)(ws + 8 * MB);
  u16* w2T    = (u16*)(ws + 10 * MB);
  u16* hb     = (u16*)(ws + 16 * MB);
  u16* kbuf   = (u16*)(ws + 48 * MB);
  u16* qbuf   = (u16*)(ws + 80 * MB);
  u16* vtbuf  = (u16*)d_out;                   // v^T (b,h,d,t) bf16

  convq_kernel<<<dim3(48, 16), 256, 0, stream>>>(wk, wq, wv, wqkvT);
  convt_kernel<<<dim3(16, 16), 256, 0, stream>>>(wproj, wprojT);
  convt_kernel<<<dim3(16, 16), 256, 0, stream>>>(w1, w1T);
  convt_kernel<<<dim3(16, 16), 256, 0, stream>>>(w2, w2T);

  // 1) hb = LN1(x) bf16
  ln_bf16_kernel<<<NTOK/4, 256, 0, stream>>>(x, ln1g, ln1b, hb);
  // 2) k,q bf16 (bhtd) + v^T bf16 (bhdt, d_out) = hb @ WqkvT^T
  mgemm_kernel<0><<<dim3(NTOK/128, 3*E_/128), 256, 0, stream>>>(
      hb, wqkvT, nullptr, nullptr, (float*)vtbuf, kbuf, qbuf);
  // 3) MFMA flash attention -> bf16 row-major into hb
  fattn_kernel<<<B_*H_, 256, 0, stream>>>(kbuf, qbuf, vtbuf, hb);
  // 4) x1 = x + attn @ wproj + bproj -> fp32 d_out (v^T dead)
  mgemm_kernel<1><<<dim3(NTOK/128, E_/128), 256, 0, stream>>>(
      hb, wprojT, bproj, x, outp, nullptr, nullptr);
  // 5) h2 = LN2(x1) bf16 (over dead k)
  ln_bf16_kernel<<<NTOK/4, 256, 0, stream>>>(outp, ln2g, ln2b, kbuf);
  // 6) ff1 = relu(h2 @ w1 + b1) bf16 (over dead q)
  mgemm_kernel<2><<<dim3(NTOK/128, E_/128), 256, 0, stream>>>(
      kbuf, w1T, b1, nullptr, nullptr, qbuf, nullptr);
  // 7) out = x1 + ff1 @ w2 + b2, in-place over d_out
  mgemm_kernel<3><<<dim3(NTOK/128, E_/128), 256, 0, stream>>>(
      qbuf, w2T, b2, nullptr, outp, nullptr, nullptr);
}

// Round 7
// 523.124 us; speedup vs baseline: 6.5080x; 1.2039x over previous
//
#include <hip/hip_runtime.h>

typedef unsigned int u32;
typedef unsigned short u16;
typedef __attribute__((ext_vector_type(8))) short bf16x8;   // 8 bf16 in 4 VGPRs
typedef __attribute__((ext_vector_type(4))) float f32x4;

#define GLOBAL_AS __attribute__((address_space(1)))
#define LDS_AS    __attribute__((address_space(3)))

#define B_   64
#define T_   256
#define E_   1024
#define H_   16
#define HD_  64
#define NTOK (B_*T_)          // 16384
#define K_   1024
#define LNEPS 1e-5f

// ---------- bf16 helpers ----------
__device__ __forceinline__ float bflo(u32 u){ return __uint_as_float(u << 16); }
__device__ __forceinline__ float bfhi(u32 u){ return __uint_as_float(u & 0xffff0000u); }
__device__ __forceinline__ u16 f2bf(float f){            // round-to-nearest-even
  u32 x = __float_as_uint(f);
  u32 r = x + 0x7fffu + ((x >> 16) & 1u);
  return (u16)(r >> 16);
}
__device__ __forceinline__ u16 f2bf_trunc(float f){      // truncate (P probs only)
  return (u16)(__float_as_uint(f) >> 16);
}
__device__ __forceinline__ u32 pack2(float a, float b){
  return (u32)f2bf(a) | ((u32)f2bf(b) << 16);
}

// async global->LDS, 16 B per lane (dest = wave-uniform base + lane*16)
__device__ __forceinline__ void gload16(const u16* g, u16* l){
  __builtin_amdgcn_global_load_lds((const GLOBAL_AS void*)g, (LDS_AS void*)l, 16, 0, 0);
}

// ---------- fused LayerNorm fp32 -> bf16, one wave per token ----------
__global__ __launch_bounds__(256) void ln_bf16_kernel(
    const float* __restrict__ x, const float* __restrict__ g,
    const float* __restrict__ b, u16* __restrict__ o)
{
  int lane  = threadIdx.x & 63;
  int token = (blockIdx.x << 2) + (threadIdx.x >> 6);
  const float4* xr = (const float4*)(x + (size_t)token * E_);
  float4 v[4];
  float s = 0.f, ss = 0.f;
  #pragma unroll
  for (int i = 0; i < 4; ++i){
    v[i] = xr[lane + 64 * i];
    s += v[i].x + v[i].y + v[i].z + v[i].w;
    ss = fmaf(v[i].x, v[i].x, fmaf(v[i].y, v[i].y,
         fmaf(v[i].z, v[i].z, fmaf(v[i].w, v[i].w, ss))));
  }
  #pragma unroll
  for (int off = 32; off > 0; off >>= 1){
    s  += __shfl_xor(s,  off);
    ss += __shfl_xor(ss, off);
  }
  float mu   = s * (1.f / E_);
  float var  = ss * (1.f / E_) - mu * mu;
  float rstd = rsqrtf(var + LNEPS);
  const float4* gr = (const float4*)g;
  const float4* br = (const float4*)b;
  uint2* orow = (uint2*)(o + (size_t)token * E_);
  #pragma unroll
  for (int i = 0; i < 4; ++i){
    float4 gg = gr[lane + 64 * i], bb = br[lane + 64 * i];
    float y0 = (v[i].x - mu) * rstd * gg.x + bb.x;
    float y1 = (v[i].y - mu) * rstd * gg.y + bb.y;
    float y2 = (v[i].z - mu) * rstd * gg.z + bb.z;
    float y3 = (v[i].w - mu) * rstd * gg.w + bb.w;
    orow[lane + 64 * i] = make_uint2(pack2(y0, y1), pack2(y2, y3));
  }
}

// ---------- weight prep (coalesced, LDS transpose) ----------
__global__ __launch_bounds__(256) void convq_kernel(
    const float* __restrict__ wk, const float* __restrict__ wq,
    const float* __restrict__ wv, u16* __restrict__ o)
{
  __shared__ float tile[64 * 68];
  const int zh = blockIdx.x, z = zh >> 4, h = zh & 15;
  const int e0 = blockIdx.y << 6;
  const float* w = (z == 0 ? wk : z == 1 ? wq : wv) + (size_t)h * (E_ * HD_);
  const int t = threadIdx.x;
  {
    int er = t >> 2, d0 = (t & 3) << 4;
    const float4* src = (const float4*)(w + (size_t)(e0 + er) * HD_ + d0);
    #pragma unroll
    for (int i = 0; i < 4; ++i)
      *(float4*)(tile + er * 68 + d0 + 4 * i) = src[i];
  }
  __syncthreads();
  {
    int dr = t >> 2, ee = (t & 3) << 4;
    u32 wd[8];
    #pragma unroll
    for (int j = 0; j < 8; ++j)
      wd[j] = pack2(tile[(ee + 2*j) * 68 + dr], tile[(ee + 2*j + 1) * 68 + dr]);
    u16* dst = o + (size_t)(z * 1024 + h * 64 + dr) * K_ + e0 + ee;
    *(uint4*)(dst    ) = make_uint4(wd[0], wd[1], wd[2], wd[3]);
    *(uint4*)(dst + 8) = make_uint4(wd[4], wd[5], wd[6], wd[7]);
  }
}

__global__ __launch_bounds__(256) void convt_kernel(
    const float* __restrict__ w, u16* __restrict__ o)
{
  __shared__ float tile[64 * 68];
  const int n0 = blockIdx.x << 6, k0 = blockIdx.y << 6;
  const int t = threadIdx.x;
  {
    int kr = t >> 2, nn = (t & 3) << 4;
    const float4* src = (const float4*)(w + (size_t)(k0 + kr) * E_ + n0 + nn);
    #pragma unroll
    for (int i = 0; i < 4; ++i)
      *(float4*)(tile + kr * 68 + nn + 4 * i) = src[i];
  }
  __syncthreads();
  {
    int nr = t >> 2, kk = (t & 3) << 4;
    u32 wd[8];
    #pragma unroll
    for (int j = 0; j < 8; ++j)
      wd[j] = pack2(tile[(kk + 2*j) * 68 + nr], tile[(kk + 2*j + 1) * 68 + nr]);
    u16* dst = o + (size_t)(n0 + nr) * K_ + k0 + kk;
    *(uint4*)(dst    ) = make_uint4(wd[0], wd[1], wd[2], wd[3]);
    *(uint4*)(dst + 8) = make_uint4(wd[4], wd[5], wd[6], wd[7]);
  }
}

// ---------- MFMA GEMM: C(M x N) = A(M x 1024) * Bt(N x 1024)^T ----------
// 128x128 tile / 256 threads, BK=64 (16 K-iters, 32 MFMA per barrier pair).
// LDS rows are 8 chunks of 16 B, XOR-swizzled: slot chunk = chunk ^ (row&7).
// MODE 0: qkv -> k,q bf16 (b,h,t,d); v bf16 TRANSPOSED (b,h,d,t); LDS-transposed stores
// MODE 1: proj -> Cf fp32 = acc + bias + resid            [row-major]
// MODE 2: ff1  -> Cb bf16 = relu(acc + bias), LDS-transposed stores
// MODE 3: ff2  -> Cf fp32 = acc + bias + Cf (in-place residual)
template<int MODE>
__global__ __launch_bounds__(256) void mgemm_kernel(
    const u16* __restrict__ A, const u16* __restrict__ Bt,
    const float* __restrict__ bias, const float* __restrict__ resid,
    float* __restrict__ Cf, u16* __restrict__ Cb, u16* __restrict__ Cb2)
{
  __shared__ __align__(16) u16 lds[16384];     // 32 KB: As | Bs, reused by epilogue
  u16* As = lds;                               // [128 rows][64 k] swizzled
  u16* Bs = lds + 8192;
  const int row0 = blockIdx.x * 128, col0 = blockIdx.y * 128;
  const int tid = threadIdx.x, lane = tid & 63;
  const int wv_ = tid >> 6, wm = wv_ >> 1, wn = wv_ & 1;
  const int l15 = lane & 15, quad = lane >> 4;

  // staging: pass p stages slot s = p*256+tid -> row = p*32 + (tid>>3),
  // chunk = (tid&7) ^ (row&7); dest is tid-linear (gload16 requirement).
  const int srow   = tid >> 3;
  const int schunk = ((tid & 7) ^ ((tid >> 3) & 7)) << 3;
  const u16* Ag = A  + (size_t)(row0 + srow) * K_ + schunk;
  const u16* Bg = Bt + (size_t)(col0 + srow) * K_ + schunk;
  u16* Ald = As + tid * 8;
  u16* Bld = Bs + tid * 8;

  f32x4 acc[4][4];
  #pragma unroll
  for (int i = 0; i < 4; ++i)
    #pragma unroll
    for (int j = 0; j < 4; ++j)
      acc[i][j] = (f32x4){0.f, 0.f, 0.f, 0.f};

  const int mrow = wm * 64, nrow = wn * 64;
  for (int k0 = 0; k0 < K_; k0 += 64) {
    __syncthreads();
    #pragma unroll
    for (int p = 0; p < 4; ++p) {
      gload16(Ag + (size_t)(p * 32) * K_ + k0, Ald + p * 2048);
      gload16(Bg + (size_t)(p * 32) * K_ + k0, Bld + p * 2048);
    }
    __syncthreads();
    #pragma unroll
    for (int ss = 0; ss < 2; ++ss) {
      bf16x8 a[4], b[4];
      #pragma unroll
      for (int i = 0; i < 4; ++i){
        int ma = mrow + i * 16 + l15, nb = nrow + i * 16 + l15;
        a[i] = *(const bf16x8*)(As + ma * 64 + ((((ss << 2) | quad)) ^ (ma & 7)) * 8);
        b[i] = *(const bf16x8*)(Bs + nb * 64 + ((((ss << 2) | quad)) ^ (nb & 7)) * 8);
      }
      #pragma unroll
      for (int i = 0; i < 4; ++i)
        #pragma unroll
        for (int j = 0; j < 4; ++j)
          acc[i][j] = __builtin_amdgcn_mfma_f32_16x16x32_bf16(a[i], b[j], acc[i][j], 0, 0, 0);
    }
  }

  if (MODE == 1 || MODE == 3) {
    // fp32 row-major epilogue (dword-coalesced scalar stores)
    #pragma unroll
    for (int j = 0; j < 4; ++j) {
      const int n = col0 + wn * 64 + j * 16 + l15;
      float bn = bias[n];
      #pragma unroll
      for (int i = 0; i < 4; ++i)
        #pragma unroll
        for (int r = 0; r < 4; ++r) {
          const int row = row0 + wm * 64 + i * 16 + quad * 4 + r;
          size_t idx = (size_t)row * E_ + n;
          float v = acc[i][j][r] + bn;
          if (MODE == 1) Cf[idx] = v + resid[idx];
          else           Cf[idx] = v + Cf[idx];
        }
    }
    return;
  }

  // ---- bf16 epilogues via per-wave 8-KB LDS transpose -> 16-B coalesced stores ----
  __syncthreads();                              // everyone done with As/Bs
  u16* ep = lds + wv_ * 4096;                   // 64x64 u16, row stride 64
  const int nb0 = col0 + wn * 64;               // wave's 64-col window (64-aligned)

  if (MODE == 2) {
    #pragma unroll
    for (int j = 0; j < 4; ++j) {
      float bn = bias[nb0 + j * 16 + l15];
      #pragma unroll
      for (int i = 0; i < 4; ++i)
        #pragma unroll
        for (int r = 0; r < 4; ++r)
          ep[(i*16 + quad*4 + r) * 64 + j*16 + l15] =
              f2bf(fmaxf(acc[i][j][r] + bn, 0.f));
    }
    __syncthreads();
    const int rbase = row0 + wm * 64;
    #pragma unroll
    for (int it = 0; it < 8; ++it) {
      int tl = it * 8 + (lane >> 3), c = lane & 7;
      uint4 v = *(const uint4*)(ep + tl * 64 + c * 8);
      *(uint4*)(Cb + (size_t)(rbase + tl) * E_ + nb0 + c * 8) = v;
    }
    return;
  }

  // MODE 0: z = 0 (k), 1 (q): row-major (b,h,t,d). z = 2 (v): transposed (b,h,d,t).
  const int z = nb0 >> 10, h = (nb0 >> 6) & 15;
  const int bb = (row0 + wm * 64) >> 8, tb0 = (row0 + wm * 64) & 255;
  if (z < 2) {
    #pragma unroll
    for (int i = 0; i < 4; ++i)
      #pragma unroll
      for (int j = 0; j < 4; ++j)
        #pragma unroll
        for (int r = 0; r < 4; ++r)
          ep[(i*16 + quad*4 + r) * 64 + j*16 + l15] = f2bf(acc[i][j][r]);
  } else {
    // write transposed [d][t], chunk-swizzled to break the 16-way write conflict
    #pragma unroll
    for (int i = 0; i < 4; ++i)
      #pragma unroll
      for (int j = 0; j < 4; ++j)
        #pragma unroll
        for (int r = 0; r < 4; ++r) {
          int tl = i*16 + quad*4 + r, d = j*16 + l15;
          int cs = (tl >> 3) ^ (d & 7);
          ep[d * 64 + cs * 8 + (tl & 7)] = f2bf(acc[i][j][r]);
        }
  }
  __syncthreads();
  if (z < 2) {
    u16* out = (z == 0 ? Cb : Cb2) + ((size_t)(bb * H_ + h) * T_ + tb0) * HD_;
    #pragma unroll
    for (int it = 0; it < 8; ++it) {
      int tl = it * 8 + (lane >> 3), c = lane & 7;
      uint4 v = *(const uint4*)(ep + tl * 64 + c * 8);
      *(uint4*)(out + (size_t)tl * HD_ + c * 8) = v;
    }
  } else {
    u16* out = (u16*)Cf + ((size_t)(bb * H_ + h) * HD_) * T_;
    #pragma unroll
    for (int it = 0; it < 8; ++it) {
      int dl = it * 8 + (lane >> 3), c = lane & 7;
      int cs = c ^ (dl & 7);
      uint4 v = *(const uint4*)(ep + dl * 64 + cs * 8);
      *(uint4*)(out + (size_t)dl * T_ + tb0 + c * 8) = v;
    }
  }
}

// ---------- MFMA flash attention: block = 4 bh's at one tblk (balanced waves) ----------
// scores[t][s] = k_t . q_s / 8 (K.Q^T per reference), causal s<=t.
// k,q bf16 (b,h,t,d); vt bf16 (b,h,d,t); out bf16 row-major (b,t,h*64+d).
// Wave w handles bh = blockIdx.x*4 + w; tblk = blockIdx.y (uniform per block),
// so loop trip count and all barriers are block-uniform AND all waves do equal work.
__global__ __launch_bounds__(256) void fattn_kernel(
    const u16* __restrict__ kk_, const u16* __restrict__ qq_,
    const u16* __restrict__ vt_, u16* __restrict__ out)
{
  __shared__ __align__(16) u16 Pb[4][64 * 72];  // per-wave private, 9216 B each
  const int tid = threadIdx.x, lane = tid & 63, wv = tid >> 6;
  const int bh = blockIdx.x * 4 + wv;
  const int tblk = blockIdx.y;
  const int l15 = lane & 15, quad = lane >> 4;
  const u16* kb  = kk_ + (size_t)bh * (T_ * HD_);
  const u16* qb  = qq_ + (size_t)bh * (T_ * HD_);
  const u16* vtb = vt_ + (size_t)bh * (HD_ * T_);
  u16* Pw = Pb[wv];

  // K fragments for this wave's t-block
  bf16x8 kf[4][2];
  #pragma unroll
  for (int i = 0; i < 4; ++i)
    #pragma unroll
    for (int c = 0; c < 2; ++c)
      kf[i][c] = *(const bf16x8*)(kb + (size_t)(tblk*64 + i*16 + l15) * HD_ + c*32 + quad*8);

  f32x4 o[4][4];
  float mrow[4][4], lrow[4][4];
  #pragma unroll
  for (int i = 0; i < 4; ++i) {
    #pragma unroll
    for (int j = 0; j < 4; ++j) o[i][j] = (f32x4){0.f, 0.f, 0.f, 0.f};
    #pragma unroll
    for (int r = 0; r < 4; ++r) { mrow[i][r] = -1e30f; lrow[i][r] = 0.f; }
  }

  for (int sb = 0; sb <= tblk; ++sb) {        // trip count uniform per block
    // ---- S = K . Q^T ----
    f32x4 S[4][4];
    #pragma unroll
    for (int j = 0; j < 4; ++j) {
      bf16x8 qf0 = *(const bf16x8*)(qb + (size_t)(sb*64 + j*16 + l15) * HD_ +      quad*8);
      bf16x8 qf1 = *(const bf16x8*)(qb + (size_t)(sb*64 + j*16 + l15) * HD_ + 32 + quad*8);
      #pragma unroll
      for (int i = 0; i < 4; ++i) {
        f32x4 t0 = __builtin_amdgcn_mfma_f32_16x16x32_bf16(kf[i][0], qf0,
                       (f32x4){0.f,0.f,0.f,0.f}, 0, 0, 0);
        S[i][j] = __builtin_amdgcn_mfma_f32_16x16x32_bf16(kf[i][1], qf1, t0, 0, 0, 0);
      }
    }
    // ---- scale + causal mask ----
    #pragma unroll
    for (int i = 0; i < 4; ++i)
      #pragma unroll
      for (int j = 0; j < 4; ++j)
        #pragma unroll
        for (int r = 0; r < 4; ++r) {
          float val = S[i][j][r] * 0.125f;
          if (sb == tblk) {
            int tl = i*16 + quad*4 + r, sl = j*16 + l15;
            if (sl > tl) val = -1e30f;
          }
          S[i][j][r] = val;
        }
    // ---- online softmax ----
    #pragma unroll
    for (int i = 0; i < 4; ++i)
      #pragma unroll
      for (int r = 0; r < 4; ++r) {
        float mx = fmaxf(fmaxf(S[i][0][r], S[i][1][r]), fmaxf(S[i][2][r], S[i][3][r]));
        #pragma unroll
        for (int msk = 1; msk < 16; msk <<= 1) mx = fmaxf(mx, __shfl_xor(mx, msk));
        float mn = fmaxf(mrow[i][r], mx);
        float al = __expf(mrow[i][r] - mn);
        mrow[i][r] = mn;
        float sm = 0.f;
        #pragma unroll
        for (int j = 0; j < 4; ++j) {
          float p = __expf(S[i][j][r] - mn);
          S[i][j][r] = p;
          sm += p;
        }
        #pragma unroll
        for (int msk = 1; msk < 16; msk <<= 1) sm += __shfl_xor(sm, msk);
        lrow[i][r] = lrow[i][r] * al + sm;
        #pragma unroll
        for (int jd = 0; jd < 4; ++jd) o[i][jd][r] *= al;
      }
    // ---- P -> private LDS ----
    #pragma unroll
    for (int i = 0; i < 4; ++i)
      #pragma unroll
      for (int j = 0; j < 4; ++j)
        #pragma unroll
        for (int r = 0; r < 4; ++r)
          Pw[(i*16 + quad*4 + r) * 72 + j*16 + l15] = f2bf_trunc(S[i][j][r]);
    __syncthreads();
    // ---- O += P . V ----
    bf16x8 pf[4][2];
    #pragma unroll
    for (int i = 0; i < 4; ++i)
      #pragma unroll
      for (int c = 0; c < 2; ++c)
        pf[i][c] = *(const bf16x8*)(Pw + (i*16 + l15) * 72 + c*32 + quad*8);
    #pragma unroll
    for (int jd = 0; jd < 4; ++jd) {
      bf16x8 vf0 = *(const bf16x8*)(vtb + (size_t)(jd*16 + l15) * T_ + sb*64 +      quad*8);
      bf16x8 vf1 = *(const bf16x8*)(vtb + (size_t)(jd*16 + l15) * T_ + sb*64 + 32 + quad*8);
      #pragma unroll
      for (int i = 0; i < 4; ++i) {
        f32x4 t0 = __builtin_amdgcn_mfma_f32_16x16x32_bf16(pf[i][0], vf0, o[i][jd], 0, 0, 0);
        o[i][jd] = __builtin_amdgcn_mfma_f32_16x16x32_bf16(pf[i][1], vf1, t0, 0, 0, 0);
      }
    }
    __syncthreads();
  }

  // ---- normalize, transpose via private LDS, coalesced store ----
  #pragma unroll
  for (int i = 0; i < 4; ++i)
    #pragma unroll
    for (int r = 0; r < 4; ++r) {
      float inv = 1.0f / lrow[i][r];
      #pragma unroll
      for (int jd = 0; jd < 4; ++jd)
        Pw[(i*16 + quad*4 + r) * 72 + jd*16 + l15] = f2bf(o[i][jd][r] * inv);
    }
  __syncthreads();
  {
    const int b = bh >> 4, h = bh & 15;
    const uint4* pr = (const uint4*)(Pw + lane * 72);
    uint4* og = (uint4*)(out + ((size_t)(b * T_ + tblk*64 + lane)) * E_ + h * HD_);
    #pragma unroll
    for (int k = 0; k < 8; ++k) og[k] = pr[k];
  }
}

// ---------- launch ----------
extern "C" void kernel_launch(void* const* d_in, const int* in_sizes, int n_in,
                              void* d_out, int out_size, void* d_ws, size_t ws_size,
                              hipStream_t stream) {
  const float* x     = (const float*)d_in[0];
  const float* ln1g  = (const float*)d_in[1];
  const float* ln1b  = (const float*)d_in[2];
  const float* wk    = (const float*)d_in[3];
  const float* wq    = (const float*)d_in[4];
  const float* wv    = (const float*)d_in[5];
  const float* wproj = (const float*)d_in[6];
  const float* bproj = (const float*)d_in[7];
  const float* ln2g  = (const float*)d_in[8];
  const float* ln2b  = (const float*)d_in[9];
  const float* w1    = (const float*)d_in[10];
  const float* b1    = (const float*)d_in[11];
  const float* w2    = (const float*)d_in[12];
  const float* b2    = (const float*)d_in[13];
  float* outp = (float*)d_out;

  // ws (112 MB <= proven 128 MB):
  //  [0,6M) WqkvT | [6,8M) WprojT | [8,10M) W1T | [10,12M) W2T
  //  [16,48M) hb bf16 (LN1 out -> attn out)
  //  [48,80M) k bf16 (bhtd) -> h2 bf16 | [80,112M) q bf16 (bhtd) -> ff1 bf16
  // d_out (64MB): v^T bf16 (b,h,d,t) [0,32M) -> x1 fp32 (full) -> out (in-place)
  char* ws = (char*)d_ws;
  const size_t MB = 1024 * 1024;
  u16* wqkvT  = (u16*)(ws);
  u16* wprojT = (u16*)(ws + 6 * MB);
  u16* w1T    = (u16*)(ws + 8 * MB);
  u16* w2T    = (u16*)(ws + 10 * MB);
  u16* hb     = (u16*)(ws + 16 * MB);
  u16* kbuf   = (u16*)(ws + 48 * MB);
  u16* qbuf   = (u16*)(ws + 80 * MB);
  u16* vtbuf  = (u16*)d_out;                   // v^T (b,h,d,t) bf16

  convq_kernel<<<dim3(48, 16), 256, 0, stream>>>(wk, wq, wv, wqkvT);
  convt_kernel<<<dim3(16, 16), 256, 0, stream>>>(wproj, wprojT);
  convt_kernel<<<dim3(16, 16), 256, 0, stream>>>(w1, w1T);
  convt_kernel<<<dim3(16, 16), 256, 0, stream>>>(w2, w2T);

  // 1) hb = LN1(x) bf16
  ln_bf16_kernel<<<NTOK/4, 256, 0, stream>>>(x, ln1g, ln1b, hb);
  // 2) k,q bf16 (bhtd) + v^T bf16 (bhdt, d_out) = hb @ WqkvT^T
  mgemm_kernel<0><<<dim3(NTOK/128, 3*E_/128), 256, 0, stream>>>(
      hb, wqkvT, nullptr, nullptr, (float*)vtbuf, kbuf, qbuf);
  // 3) MFMA flash attention (balanced) -> bf16 row-major into hb
  fattn_kernel<<<dim3(B_*H_/4, 4), 256, 0, stream>>>(kbuf, qbuf, vtbuf, hb);
  // 4) x1 = x + attn @ wproj + bproj -> fp32 d_out (v^T dead)
  mgemm_kernel<1><<<dim3(NTOK/128, E_/128), 256, 0, stream>>>(
      hb, wprojT, bproj, x, outp, nullptr, nullptr);
  // 5) h2 = LN2(x1) bf16 (over dead k)
  ln_bf16_kernel<<<NTOK/4, 256, 0, stream>>>(outp, ln2g, ln2b, kbuf);
  // 6) ff1 = relu(h2 @ w1 + b1) bf16 (over dead q)
  mgemm_kernel<2><<<dim3(NTOK/128, E_/128), 256, 0, stream>>>(
      kbuf, w1T, b1, nullptr, nullptr, qbuf, nullptr);
  // 7) out = x1 + ff1 @ w2 + b2, in-place over d_out
  mgemm_kernel<3><<<dim3(NTOK/128, E_/128), 256, 0, stream>>>(
      qbuf, w2T, b2, nullptr, outp, nullptr, nullptr);
}